// Round 5
// baseline (281.188 us; speedup 1.0000x reference)
//
#include <hip/hip_runtime.h>
#include <hip/hip_bf16.h>

#define BATCH 8
#define NPTS 2048
#define LATENT 128

typedef __attribute__((ext_vector_type(8))) short short8;
typedef __attribute__((ext_vector_type(4))) float f32x4;

__device__ __forceinline__ ushort f2bf(float f) {
  unsigned int b = __float_as_uint(f);
  b += 0x7FFF + ((b >> 16) & 1);
  return (ushort)(b >> 16);
}

// ---------------------------------------------------------------------------
// prep: centroid + write pnt[b][n] = (sqrt2*xc, -|xc|^2) so that
// -dist_ij = pi.w + pj.w + dot(pi.xyz, pj.xyz). One block per batch.
// ---------------------------------------------------------------------------
__global__ __launch_bounds__(256) void prep_kernel(const float* __restrict__ x,
    const float* __restrict__ mask, float4* __restrict__ pnt) {
  const int b = blockIdx.x;
  const int tid = threadIdx.x;
  const float* xb = x + (size_t)b * NPTS * 3;
  const float* mb = mask + (size_t)b * NPTS;
  float s0 = 0.f, s1 = 0.f, s2 = 0.f, c = 0.f;
  for (int n = tid; n < NPTS; n += 256) {
    float m = mb[n];
    s0 += xb[n * 3 + 0] * m;
    s1 += xb[n * 3 + 1] * m;
    s2 += xb[n * 3 + 2] * m;
    c += m;
  }
  __shared__ float red[4][256];
  red[0][tid] = s0; red[1][tid] = s1; red[2][tid] = s2; red[3][tid] = c;
  __syncthreads();
  for (int off = 128; off > 0; off >>= 1) {
    if (tid < off) {
      red[0][tid] += red[0][tid + off];
      red[1][tid] += red[1][tid + off];
      red[2][tid] += red[2][tid + off];
      red[3][tid] += red[3][tid + off];
    }
    __syncthreads();
  }
  const float cnt = fmaxf(red[3][0], 1.0f);
  const float c0 = red[0][0] / cnt, c1 = red[1][0] / cnt, c2 = red[2][0] / cnt;
  const float SQ2 = 1.41421356237f;
  float4* pb = pnt + (size_t)b * NPTS;
  for (int n = tid; n < NPTS; n += 256) {
    const float a0 = xb[n * 3 + 0] - c0;
    const float a1 = xb[n * 3 + 1] - c1;
    const float a2 = xb[n * 3 + 2] - c2;
    pb[n] = make_float4(a0 * SQ2, a1 * SQ2, a2 * SQ2,
                        -(a0 * a0 + a1 * a1 + a2 * a2));
  }
}

// ---------------------------------------------------------------------------
// W transpose to bf16: WT[n][k] = bf16(W[k][n]); 64x64 LDS tiles.
// ---------------------------------------------------------------------------
__global__ __launch_bounds__(256) void wtrans_kernel(const float* __restrict__ W,
    ushort* __restrict__ WT, int K, int N) {
  __shared__ ushort s[64][72];
  const int tid = threadIdx.x;
  const int n0 = blockIdx.x * 64, k0 = blockIdx.y * 64;
  for (int i = tid; i < 64 * 64; i += 256) {
    const int kl = i >> 6, nl = i & 63;
    s[kl][nl] = f2bf(W[(size_t)(k0 + kl) * N + n0 + nl]);
  }
  __syncthreads();
  for (int i = tid; i < 64 * 64; i += 256) {
    const int nl = i >> 6, kl = i & 63;
    WT[(size_t)(n0 + nl) * K + k0 + kl] = s[kl][nl];
  }
}

// ---------------------------------------------------------------------------
// layer-0 aggregation (h == xc, D=3): 64 rows/block, 4-way j-split.
// ---------------------------------------------------------------------------
__global__ __launch_bounds__(256) void agg3_kernel(const float4* __restrict__ pnt,
    float* __restrict__ hagg0) {
  const int b = blockIdx.y;
  const int i0 = blockIdx.x * 64;
  const int tid = threadIdx.x;
  const int il = tid & 63, part = tid >> 6;
  const float4* pb = pnt + (size_t)b * NPTS;
  const float4 pi = pb[i0 + il];
  float a0 = 0.f, a1 = 0.f, a2 = 0.f, dn = 0.f;
#pragma unroll 8
  for (int j = part * 512; j < part * 512 + 512; j++) {
    const float4 pj = pb[j];
    float arg = pi.w + pj.w;
    arg = fmaf(pi.x, pj.x, arg);
    arg = fmaf(pi.y, pj.y, arg);
    arg = fmaf(pi.z, pj.z, arg);
    const float w = __expf(arg);
    a0 = fmaf(w, pj.x, a0);
    a1 = fmaf(w, pj.y, a1);
    a2 = fmaf(w, pj.z, a2);
    dn += w;
  }
  __shared__ float4 sred[64][4];
  sred[il][part] = make_float4(a0, a1, a2, dn);
  __syncthreads();
  if (tid < 64) {
    const float4 r0 = sred[tid][0], r1 = sred[tid][1];
    const float4 r2 = sred[tid][2], r3 = sred[tid][3];
    const float A0 = (r0.x + r1.x) + (r2.x + r3.x);
    const float A1 = (r0.y + r1.y) + (r2.y + r3.y);
    const float A2 = (r0.z + r1.z) + (r2.z + r3.z);
    const float DN = (r0.w + r1.w) + (r2.w + r3.w);
    const float inv = 1.0f / (DN * 1.41421356237f);  // undo sqrt2 scaling
    float* op = hagg0 + ((size_t)b * NPTS + i0 + tid) * 3;
    op[0] = A0 * inv; op[1] = A1 * inv; op[2] = A2 * inv;
  }
}

// ---------------------------------------------------------------------------
// layer-0 dense + LN + swish (DIN=3 -> DOUT=64), 16 rows/block,
// writes transposed bf16 h1T[b][d][n].
// ---------------------------------------------------------------------------
__global__ __launch_bounds__(256) void mlp0_kernel(
    const float* __restrict__ in0, const float* __restrict__ W,
    const float* __restrict__ bias, const float* __restrict__ g,
    const float* __restrict__ be, ushort* __restrict__ hout) {
  constexpr int DIN = 3, DOUT = 64;
  const int tid = threadIdx.x;
  const int wv = tid >> 6, lane = tid & 63;
  const int r0 = blockIdx.x * 16;
  __shared__ float srow[16 * DIN];
  if (tid < 16 * DIN) srow[tid] = in0[(size_t)r0 * DIN + tid];
  __syncthreads();

  float o[4];
  const float bv = bias[lane];
#pragma unroll
  for (int r = 0; r < 4; r++) o[r] = bv;
#pragma unroll
  for (int k = 0; k < DIN; k++) {
    const float wk = W[(size_t)k * DOUT + lane];
#pragma unroll
    for (int r = 0; r < 4; r++)
      o[r] = fmaf(srow[(wv * 4 + r) * DIN + k], wk, o[r]);
  }
  __shared__ ushort lt[16][DOUT];
#pragma unroll
  for (int r = 0; r < 4; r++) {
    float m1 = o[r], m2 = o[r] * o[r];
#pragma unroll
    for (int off = 32; off > 0; off >>= 1) {
      m1 += __shfl_xor(m1, off, 64);
      m2 += __shfl_xor(m2, off, 64);
    }
    const float mu = m1 / DOUT;
    const float var = m2 / DOUT - mu * mu;
    const float rstd = rsqrtf(var + 1e-6f);
    const float v = (o[r] - mu) * rstd * g[lane] + be[lane];
    const float act = v / (1.0f + __expf(-v));
    lt[wv * 4 + r][lane] = f2bf(act);
  }
  __syncthreads();
  if (tid < DOUT) {
    ushort tmp[16];
#pragma unroll
    for (int r = 0; r < 16; r++) tmp[r] = lt[r][tid];
    const int bb = r0 / NPTS;
    const int nn = r0 % NPTS;
    ushort* dst = hout + ((size_t)bb * DOUT + tid) * NPTS + nn;
    *(uint4*)dst = *(uint4*)&tmp[0];
    *(uint4*)(dst + 8) = *(uint4*)&tmp[8];
  }
}

// ---------------------------------------------------------------------------
// FUSED layer v2: MFMA aggregation (register-prefetch pipelined) +
// MFMA dense (bf16 WT) + LN + swish (+ pooled partial).
// Block = 32 rows, 4 waves = {row-group gq} x {j-half hf}.
// LDS regions aliased by liveness: staging (loop) vs snum/srow/lt (epilogue).
// ---------------------------------------------------------------------------
template <int DIN, int DOUT, bool POOL>
__global__ __launch_bounds__(256, 2) void fused_layer(
    const float4* __restrict__ pnt, const ushort* __restrict__ hT,
    const ushort* __restrict__ WT, const float* __restrict__ bias,
    const float* __restrict__ g, const float* __restrict__ be,
    ushort* __restrict__ hout, const float* __restrict__ mask,
    float* __restrict__ partial) {
  constexpr int NT = DIN / 16;
  constexpr int HALF = NPTS / 2;
  constexpr int TILES = HALF / 64;      // 16
  constexpr int CT = DOUT / 16;
  constexpr int NCOL = CT / 2;          // col-tiles per wave
  constexpr int PS = DIN + 16;          // srow pitch (ushorts)
  constexpr int SHT_B = 2 * DIN * 72 * 2;
  constexpr int SNUM_B = 2 * 32 * DIN * 4;
  constexpr int OFF_SROW = SNUM_B + 896;
  constexpr int LOOP_B = SHT_B + 2048;
  constexpr int EPI_B = OFF_SROW + 32 * PS * 2;
  constexpr int SMEM_B = LOOP_B > EPI_B ? LOOP_B : EPI_B;
  __shared__ __align__(16) char smem[SMEM_B];
  ushort* sht = (ushort*)smem;                    // [2][DIN][72]
  float4* spnt = (float4*)(smem + SHT_B);         // [2][64] swizzled

  const int b = blockIdx.y;
  const int i0 = blockIdx.x * 32;
  const int tid = threadIdx.x;
  const int wv = tid >> 6, lane = tid & 63;
  const int gq = wv & 1;    // row group (16 rows)
  const int hf = wv >> 1;   // j half
  const int m = lane & 15, q = lane >> 4;
  const float4* pb = pnt + (size_t)b * NPTS;
  const ushort* hb = hT + (size_t)b * DIN * NPTS;

  const float4 pi = pb[i0 + gq * 16 + m];   // my A-row's point

  f32x4 acc[NT];
#pragma unroll
  for (int nt = 0; nt < NT; nt++)
#pragma unroll
    for (int e = 0; e < 4; e++) acc[nt][e] = 0.f;
  float dacc = 0.f;

  const int sc = tid & 7;       // 16B chunk within 64-j row
  const int sd = tid >> 3;      // 0..31 d-row

  uint4 pref[2][DIN / 32];
  float4 ppref;

  auto gload = [&](int t) {
#pragma unroll
    for (int h2 = 0; h2 < 2; h2++) {
      const int jb = h2 * HALF + t * 64;
#pragma unroll
      for (int i = 0; i < DIN / 32; i++)
        pref[h2][i] = *(const uint4*)(hb + (size_t)(i * 32 + sd) * NPTS + jb + sc * 8);
    }
    if (tid < 128) ppref = pb[(tid >> 6) * HALF + t * 64 + (tid & 63)];
  };
  auto lwrite = [&]() {
#pragma unroll
    for (int h2 = 0; h2 < 2; h2++)
#pragma unroll
      for (int i = 0; i < DIN / 32; i++)
        *(uint4*)&sht[(size_t)h2 * DIN * 72 + (i * 32 + sd) * 72 + sc * 8] = pref[h2][i];
    if (tid < 128) {
      const int jj = tid & 63;
      spnt[(tid >> 6) * 64 + (((jj & 7) << 3) | (jj >> 3))] = ppref;
    }
  };

  gload(0);
  lwrite();
  __syncthreads();
  for (int t = 0; t < TILES; t++) {
    if (t + 1 < TILES) gload(t + 1);   // global -> regs, hidden behind compute
#pragma unroll
    for (int s = 0; s < 2; s++) {
      short8 af;
#pragma unroll
      for (int jj = 0; jj < 8; jj++) {
        const float4 pj = spnt[hf * 64 + ((jj << 3) | (s * 4 + q))];
        float arg = pi.w + pj.w;
        arg = fmaf(pi.x, pj.x, arg);
        arg = fmaf(pi.y, pj.y, arg);
        arg = fmaf(pi.z, pj.z, arg);
        const float w = __expf(arg);   // exp(-dist_ij)
        dacc += w;
        af[jj] = (short)f2bf(w);
      }
#pragma unroll
      for (int nt = 0; nt < NT; nt++) {
        const short8 bfr = *(const short8*)&sht[(size_t)hf * DIN * 72 + (nt * 16 + m) * 72 + s * 32 + q * 8];
        acc[nt] = __builtin_amdgcn_mfma_f32_16x16x32_bf16(af, bfr, acc[nt], 0, 0, 0);
      }
    }
    __syncthreads();
    if (t + 1 < TILES) {
      lwrite();                         // regs -> LDS
      __syncthreads();
    }
  }

  // ---- combine split-K partials in LDS (aliased over dead staging) ----
  float* snum = (float*)smem;                    // [2][32][DIN]
  float* sden = (float*)(smem + SNUM_B);         // [2][32]
  float* sinv = (float*)(smem + SNUM_B + 256);   // [32]
  float* sstat = (float*)(smem + SNUM_B + 384);  // [32][2][2]
  ushort* srow = (ushort*)(smem + OFF_SROW);     // [32][PS] bf16

  dacc += __shfl_xor(dacc, 16, 64);
  dacc += __shfl_xor(dacc, 32, 64);
  if (q == 0) sden[hf * 32 + gq * 16 + m] = dacc;
  // agg C/D layout: col = lane&15 (d), row = q*4 + reg
#pragma unroll
  for (int nt = 0; nt < NT; nt++)
#pragma unroll
    for (int r = 0; r < 4; r++)
      snum[((size_t)hf * 32 + gq * 16 + q * 4 + r) * DIN + nt * 16 + m] = acc[nt][r];
  __syncthreads();
  if (tid < 32) sinv[tid] = 1.0f / (sden[tid] + sden[32 + tid]);
  __syncthreads();
  for (int idx = tid; idx < 32 * DIN; idx += 256) {
    const int r = idx / DIN;
    srow[r * PS + (idx & (DIN - 1))] =
        f2bf((snum[idx] + snum[32 * DIN + idx]) * sinv[r]);
  }
  __syncthreads();

  // ---- dense via MFMA: C[32 x DOUT] = srow @ W; wave: rows gq*16..+15,
  //      col-tiles hf*NCOL..+NCOL-1 ----
  short8 afrag[DIN / 32];
#pragma unroll
  for (int kt = 0; kt < DIN / 32; kt++)
    afrag[kt] = *(const short8*)&srow[(gq * 16 + m) * PS + kt * 32 + q * 8];
  f32x4 oacc[NCOL];
#pragma unroll
  for (int c = 0; c < NCOL; c++)
#pragma unroll
    for (int e = 0; e < 4; e++) oacc[c][e] = 0.f;
#pragma unroll
  for (int c = 0; c < NCOL; c++) {
    const int n0 = (hf * NCOL + c) * 16;
#pragma unroll
    for (int kt = 0; kt < DIN / 32; kt++) {
      const short8 bfrag = *(const short8*)(WT + (size_t)(n0 + m) * DIN + kt * 32 + q * 8);
      oacc[c] = __builtin_amdgcn_mfma_f32_16x16x32_bf16(afrag[kt], bfrag, oacc[c], 0, 0, 0);
    }
  }

  // ---- LN stats: per-row mean/var across both col-halves via LDS ----
  float bcol[NCOL];
#pragma unroll
  for (int c = 0; c < NCOL; c++) bcol[c] = bias[(hf * NCOL + c) * 16 + m];
#pragma unroll
  for (int r = 0; r < 4; r++) {
    float m1 = 0.f, m2 = 0.f;
#pragma unroll
    for (int c = 0; c < NCOL; c++) {
      const float v = oacc[c][r] + bcol[c];
      m1 += v; m2 += v * v;
    }
#pragma unroll
    for (int off = 8; off > 0; off >>= 1) {   // reduce over 16 m-lanes
      m1 += __shfl_xor(m1, off, 64);
      m2 += __shfl_xor(m2, off, 64);
    }
    if (m == 0) {
      const int row = gq * 16 + q * 4 + r;
      sstat[(row * 2 + hf) * 2 + 0] = m1;
      sstat[(row * 2 + hf) * 2 + 1] = m2;
    }
  }
  __syncthreads();

  ushort* lt = (ushort*)smem;   // [32][DOUT], aliases dead snum
  float* sp = (float*)smem;     // [2][DOUT] for POOL
  float pacc[NCOL];
  if (POOL) {
#pragma unroll
    for (int c = 0; c < NCOL; c++) pacc[c] = 0.f;
  }
#pragma unroll
  for (int r = 0; r < 4; r++) {
    const int row = gq * 16 + q * 4 + r;
    const float m1 = sstat[(row * 2 + 0) * 2 + 0] + sstat[(row * 2 + 1) * 2 + 0];
    const float m2 = sstat[(row * 2 + 0) * 2 + 1] + sstat[(row * 2 + 1) * 2 + 1];
    const float mu = m1 / DOUT;
    const float rstd = rsqrtf(m2 / DOUT - mu * mu + 1e-6f);
    float mval = 0.f;
    if (POOL) mval = mask[(size_t)b * NPTS + i0 + row];
#pragma unroll
    for (int c = 0; c < NCOL; c++) {
      const int dco = (hf * NCOL + c) * 16 + m;
      const float v = (oacc[c][r] + bcol[c] - mu) * rstd * g[dco] + be[dco];
      const float act = v / (1.0f + __expf(-v));
      if (POOL) pacc[c] = fmaf(act, mval, pacc[c]);
      else lt[row * DOUT + dco] = f2bf(act);
    }
  }
  if (POOL) {
#pragma unroll
    for (int c = 0; c < NCOL; c++) {
      float v = pacc[c];
      v += __shfl_xor(v, 16, 64);
      v += __shfl_xor(v, 32, 64);   // sum over q -> 16 rows of this wave
      if (q == 0) sp[gq * DOUT + (hf * NCOL + c) * 16 + m] = v;
    }
    __syncthreads();
    if (tid < DOUT)
      partial[((size_t)b * (NPTS / 32) + blockIdx.x) * DOUT + tid] =
          sp[tid] + sp[DOUT + tid];
  } else {
    __syncthreads();
    if (tid < DOUT) {
      ushort tmp[32];
#pragma unroll
      for (int r = 0; r < 32; r++) tmp[r] = lt[r * DOUT + tid];
      ushort* dst = hout + ((size_t)b * DOUT + tid) * NPTS + i0;
#pragma unroll
      for (int c = 0; c < 4; c++)
        *(uint4*)(dst + c * 8) = *(uint4*)&tmp[c * 8];
    }
  }
}

// ---------------------------------------------------------------------------
// readout: reduce 64 partial rows per batch, divide by count, Dense(256->128)
// ---------------------------------------------------------------------------
__global__ __launch_bounds__(256) void readout_kernel(
    const float* __restrict__ partial, const float* __restrict__ mask,
    const float* __restrict__ Wz, const float* __restrict__ bz,
    float* __restrict__ out) {
  const int b = blockIdx.x;
  const int tid = threadIdx.x;
  const float* pb = partial + (size_t)b * (NPTS / 32) * 256;
  float s0 = 0.f, s1 = 0.f, s2 = 0.f, s3 = 0.f;
#pragma unroll 4
  for (int p = 0; p < NPTS / 32; p += 4) {
    s0 += pb[(size_t)(p + 0) * 256 + tid];
    s1 += pb[(size_t)(p + 1) * 256 + tid];
    s2 += pb[(size_t)(p + 2) * 256 + tid];
    s3 += pb[(size_t)(p + 3) * 256 + tid];
  }
  const float s = (s0 + s1) + (s2 + s3);
  const float* mb = mask + (size_t)b * NPTS;
  float c = 0.f;
  for (int n = tid; n < NPTS; n += 256) c += mb[n];
  __shared__ float red[256];
  red[tid] = c;
  __syncthreads();
  for (int off = 128; off > 0; off >>= 1) {
    if (tid < off) red[tid] += red[tid + off];
    __syncthreads();
  }
  const float cnt = fmaxf(red[0], 1.0f);
  __shared__ float gf[256];
  gf[tid] = s / cnt;
  __syncthreads();
  if (tid < LATENT) {
    float z = bz[tid];
#pragma unroll 4
    for (int d = 0; d < 256; d++) z += gf[d] * Wz[(size_t)d * LATENT + tid];
    out[(size_t)b * LATENT + tid] = z;
  }
}

// ---------------------------------------------------------------------------
extern "C" void kernel_launch(void* const* d_in, const int* in_sizes, int n_in,
                              void* d_out, int out_size, void* d_ws, size_t ws_size,
                              hipStream_t stream) {
  const float* x    = (const float*)d_in[0];
  const float* mask = (const float*)d_in[1];
  const float* W0   = (const float*)d_in[2];
  const float* b0   = (const float*)d_in[3];
  const float* g0   = (const float*)d_in[4];
  const float* be0  = (const float*)d_in[5];
  const float* W1   = (const float*)d_in[6];
  const float* b1   = (const float*)d_in[7];
  const float* g1   = (const float*)d_in[8];
  const float* be1  = (const float*)d_in[9];
  const float* W2   = (const float*)d_in[10];
  const float* b2   = (const float*)d_in[11];
  const float* g2   = (const float*)d_in[12];
  const float* be2  = (const float*)d_in[13];
  const float* Wz   = (const float*)d_in[14];
  const float* bz   = (const float*)d_in[15];
  float* out = (float*)d_out;

  // workspace layout (bytes, 16B-aligned regions)
  char* ws = (char*)d_ws;
  float4* pnt     = (float4*)(ws);             // 262144
  float*  hagg0   = (float*)(ws + 262144);     // 196608
  ushort* h1T     = (ushort*)(ws + 458752);    // 2097152
  ushort* h2T     = (ushort*)(ws + 2555904);   // 4194304
  float*  partial = (float*)(ws + 6750208);    // 524288
  ushort* WT1     = (ushort*)(ws + 7274496);   // 64*128*2  = 16384
  ushort* WT2     = (ushort*)(ws + 7290880);   // 128*256*2 = 65536
  // total ~7.4 MB

  prep_kernel<<<dim3(BATCH), dim3(256), 0, stream>>>(x, mask, pnt);
  wtrans_kernel<<<dim3(128 / 64, 64 / 64), dim3(256), 0, stream>>>(W1, WT1, 64, 128);
  wtrans_kernel<<<dim3(256 / 64, 128 / 64), dim3(256), 0, stream>>>(W2, WT2, 128, 256);

  // layer 0: h = xc (D=3), VALU fp32
  agg3_kernel<<<dim3(NPTS / 64, BATCH), dim3(256), 0, stream>>>(pnt, hagg0);
  mlp0_kernel<<<dim3(BATCH * NPTS / 16), dim3(256), 0, stream>>>(
      hagg0, W0, b0, g0, be0, h1T);

  // layer 1 (64 -> 128): fused MFMA agg + MFMA dense + LN + swish
  fused_layer<64, 128, false><<<dim3(NPTS / 32, BATCH), dim3(256), 0, stream>>>(
      pnt, h1T, WT1, b1, g1, be1, h2T, nullptr, nullptr);

  // layer 2 (128 -> 256): fused + masked-sum pooling
  fused_layer<128, 256, true><<<dim3(NPTS / 32, BATCH), dim3(256), 0, stream>>>(
      pnt, h2T, WT2, b2, g2, be2, nullptr, mask, partial);

  // readout
  readout_kernel<<<dim3(BATCH), dim3(256), 0, stream>>>(partial, mask, Wz, bz, out);
}

// Round 6
// 227.226 us; speedup vs baseline: 1.2375x; 1.2375x over previous
//
#include <hip/hip_runtime.h>
#include <hip/hip_bf16.h>

#define BATCH 8
#define NPTS 2048
#define LATENT 128

typedef __attribute__((ext_vector_type(8))) short short8;
typedef __attribute__((ext_vector_type(4))) float f32x4;

__device__ __forceinline__ ushort f2bf(float f) {
  unsigned int b = __float_as_uint(f);
  b += 0x7FFF + ((b >> 16) & 1);
  return (ushort)(b >> 16);
}

// ---------------------------------------------------------------------------
// prep: centroid + write pnt[b][n] = (sqrt2*xc, -|xc|^2) so that
// -dist_ij = pi.w + pj.w + dot(pi.xyz, pj.xyz). One block per batch.
// ---------------------------------------------------------------------------
__global__ __launch_bounds__(256) void prep_kernel(const float* __restrict__ x,
    const float* __restrict__ mask, float4* __restrict__ pnt) {
  const int b = blockIdx.x;
  const int tid = threadIdx.x;
  const float* xb = x + (size_t)b * NPTS * 3;
  const float* mb = mask + (size_t)b * NPTS;
  float s0 = 0.f, s1 = 0.f, s2 = 0.f, c = 0.f;
  for (int n = tid; n < NPTS; n += 256) {
    float m = mb[n];
    s0 += xb[n * 3 + 0] * m;
    s1 += xb[n * 3 + 1] * m;
    s2 += xb[n * 3 + 2] * m;
    c += m;
  }
  __shared__ float red[4][256];
  red[0][tid] = s0; red[1][tid] = s1; red[2][tid] = s2; red[3][tid] = c;
  __syncthreads();
  for (int off = 128; off > 0; off >>= 1) {
    if (tid < off) {
      red[0][tid] += red[0][tid + off];
      red[1][tid] += red[1][tid + off];
      red[2][tid] += red[2][tid + off];
      red[3][tid] += red[3][tid + off];
    }
    __syncthreads();
  }
  const float cnt = fmaxf(red[3][0], 1.0f);
  const float c0 = red[0][0] / cnt, c1 = red[1][0] / cnt, c2 = red[2][0] / cnt;
  const float SQ2 = 1.41421356237f;
  float4* pb = pnt + (size_t)b * NPTS;
  for (int n = tid; n < NPTS; n += 256) {
    const float a0 = xb[n * 3 + 0] - c0;
    const float a1 = xb[n * 3 + 1] - c1;
    const float a2 = xb[n * 3 + 2] - c2;
    pb[n] = make_float4(a0 * SQ2, a1 * SQ2, a2 * SQ2,
                        -(a0 * a0 + a1 * a1 + a2 * a2));
  }
}

// ---------------------------------------------------------------------------
// W transpose to bf16: WT[n][k] = bf16(W[k][n]); 64x64 LDS tiles.
// ---------------------------------------------------------------------------
__global__ __launch_bounds__(256) void wtrans_kernel(const float* __restrict__ W,
    ushort* __restrict__ WT, int K, int N) {
  __shared__ ushort s[64][72];
  const int tid = threadIdx.x;
  const int n0 = blockIdx.x * 64, k0 = blockIdx.y * 64;
  for (int i = tid; i < 64 * 64; i += 256) {
    const int kl = i >> 6, nl = i & 63;
    s[kl][nl] = f2bf(W[(size_t)(k0 + kl) * N + n0 + nl]);
  }
  __syncthreads();
  for (int i = tid; i < 64 * 64; i += 256) {
    const int nl = i >> 6, kl = i & 63;
    WT[(size_t)(n0 + nl) * K + k0 + kl] = s[kl][nl];
  }
}

// ---------------------------------------------------------------------------
// layer-0 aggregation (h == xc, D=3): 64 rows/block, 4-way j-split.
// ---------------------------------------------------------------------------
__global__ __launch_bounds__(256) void agg3_kernel(const float4* __restrict__ pnt,
    float* __restrict__ hagg0) {
  const int b = blockIdx.y;
  const int i0 = blockIdx.x * 64;
  const int tid = threadIdx.x;
  const int il = tid & 63, part = tid >> 6;
  const float4* pb = pnt + (size_t)b * NPTS;
  const float4 pi = pb[i0 + il];
  float a0 = 0.f, a1 = 0.f, a2 = 0.f, dn = 0.f;
#pragma unroll 8
  for (int j = part * 512; j < part * 512 + 512; j++) {
    const float4 pj = pb[j];
    float arg = pi.w + pj.w;
    arg = fmaf(pi.x, pj.x, arg);
    arg = fmaf(pi.y, pj.y, arg);
    arg = fmaf(pi.z, pj.z, arg);
    const float w = __expf(arg);
    a0 = fmaf(w, pj.x, a0);
    a1 = fmaf(w, pj.y, a1);
    a2 = fmaf(w, pj.z, a2);
    dn += w;
  }
  __shared__ float4 sred[64][4];
  sred[il][part] = make_float4(a0, a1, a2, dn);
  __syncthreads();
  if (tid < 64) {
    const float4 r0 = sred[tid][0], r1 = sred[tid][1];
    const float4 r2 = sred[tid][2], r3 = sred[tid][3];
    const float A0 = (r0.x + r1.x) + (r2.x + r3.x);
    const float A1 = (r0.y + r1.y) + (r2.y + r3.y);
    const float A2 = (r0.z + r1.z) + (r2.z + r3.z);
    const float DN = (r0.w + r1.w) + (r2.w + r3.w);
    const float inv = 1.0f / (DN * 1.41421356237f);  // undo sqrt2 scaling
    float* op = hagg0 + ((size_t)b * NPTS + i0 + tid) * 3;
    op[0] = A0 * inv; op[1] = A1 * inv; op[2] = A2 * inv;
  }
}

// ---------------------------------------------------------------------------
// layer-0 dense + LN + swish (DIN=3 -> DOUT=64), 16 rows/block,
// writes transposed bf16 h1T[b][d][n].
// ---------------------------------------------------------------------------
__global__ __launch_bounds__(256) void mlp0_kernel(
    const float* __restrict__ in0, const float* __restrict__ W,
    const float* __restrict__ bias, const float* __restrict__ g,
    const float* __restrict__ be, ushort* __restrict__ hout) {
  constexpr int DIN = 3, DOUT = 64;
  const int tid = threadIdx.x;
  const int wv = tid >> 6, lane = tid & 63;
  const int r0 = blockIdx.x * 16;
  __shared__ float srow[16 * DIN];
  if (tid < 16 * DIN) srow[tid] = in0[(size_t)r0 * DIN + tid];
  __syncthreads();

  float o[4];
  const float bv = bias[lane];
#pragma unroll
  for (int r = 0; r < 4; r++) o[r] = bv;
#pragma unroll
  for (int k = 0; k < DIN; k++) {
    const float wk = W[(size_t)k * DOUT + lane];
#pragma unroll
    for (int r = 0; r < 4; r++)
      o[r] = fmaf(srow[(wv * 4 + r) * DIN + k], wk, o[r]);
  }
  __shared__ ushort lt[16][DOUT];
#pragma unroll
  for (int r = 0; r < 4; r++) {
    float m1 = o[r], m2 = o[r] * o[r];
#pragma unroll
    for (int off = 32; off > 0; off >>= 1) {
      m1 += __shfl_xor(m1, off, 64);
      m2 += __shfl_xor(m2, off, 64);
    }
    const float mu = m1 / DOUT;
    const float var = m2 / DOUT - mu * mu;
    const float rstd = rsqrtf(var + 1e-6f);
    const float v = (o[r] - mu) * rstd * g[lane] + be[lane];
    const float act = v / (1.0f + __expf(-v));
    lt[wv * 4 + r][lane] = f2bf(act);
  }
  __syncthreads();
  if (tid < DOUT) {
    ushort tmp[16];
#pragma unroll
    for (int r = 0; r < 16; r++) tmp[r] = lt[r][tid];
    const int bb = r0 / NPTS;
    const int nn = r0 % NPTS;
    ushort* dst = hout + ((size_t)bb * DOUT + tid) * NPTS + nn;
    *(uint4*)dst = *(uint4*)&tmp[0];
    *(uint4*)(dst + 8) = *(uint4*)&tmp[8];
  }
}

// ---------------------------------------------------------------------------
// FUSED layer v3: MFMA aggregation with DOUBLE-BUFFERED LDS staging (no
// cross-tile register liveness -> no scratch spill) + MFMA dense (bf16 WT)
// + LN + swish (+ pooled partial).
// Block = 32 rows, 4 waves = {row-group gq} x {j-half hf}; one barrier/tile.
// ---------------------------------------------------------------------------
template <int DIN, int DOUT, bool POOL>
__global__ __launch_bounds__(256, 2) void fused_layer(
    const float4* __restrict__ pnt, const ushort* __restrict__ hT,
    const ushort* __restrict__ WT, const float* __restrict__ bias,
    const float* __restrict__ g, const float* __restrict__ be,
    ushort* __restrict__ hout, const float* __restrict__ mask,
    float* __restrict__ partial) {
  constexpr int NT = DIN / 16;
  constexpr int HALF = NPTS / 2;
  constexpr int TILES = HALF / 64;      // 16
  constexpr int CT = DOUT / 16;
  constexpr int NCOL = CT / 2;          // col-tiles per wave
  constexpr int PS = DIN + 16;          // srow pitch (ushorts)
  constexpr int SHT_B = 2 * 2 * DIN * 72 * 2;   // [buf][half][DIN][72] ushort
  constexpr int SPNT_B = 2 * 2 * 64 * 16;       // [buf][half][64] float4
  constexpr int LOOP_B = SHT_B + SPNT_B;
  constexpr int SNUM_B = 2 * 32 * DIN * 4;
  constexpr int OFF_SROW = SNUM_B + 896;
  constexpr int EPI_B = OFF_SROW + 32 * PS * 2;
  constexpr int SMEM_B = LOOP_B > EPI_B ? LOOP_B : EPI_B;
  __shared__ __align__(16) char smem[SMEM_B];
  ushort* sht = (ushort*)smem;                    // [buf][half][DIN][72]
  float4* spnt = (float4*)(smem + SHT_B);         // [buf][half][64] swizzled

  const int b = blockIdx.y;
  const int i0 = blockIdx.x * 32;
  const int tid = threadIdx.x;
  const int wv = tid >> 6, lane = tid & 63;
  const int gq = wv & 1;    // row group (16 rows)
  const int hf = wv >> 1;   // j half
  const int m = lane & 15, q = lane >> 4;
  const float4* pb = pnt + (size_t)b * NPTS;
  const ushort* hb = hT + (size_t)b * DIN * NPTS;

  const float4 pi = pb[i0 + gq * 16 + m];   // my A-row's point

  f32x4 acc[NT];
#pragma unroll
  for (int nt = 0; nt < NT; nt++)
#pragma unroll
    for (int e = 0; e < 4; e++) acc[nt][e] = 0.f;
  float dacc = 0.f;

  const int sc = tid & 7;       // 16B chunk within 64-j row
  const int sd = tid >> 3;      // 0..31 d-row

  // load global -> VGPR -> LDS immediately (registers die right away)
  auto stage = [&](int t, int bf) {
    const int jb = t * 64;
#pragma unroll
    for (int h2 = 0; h2 < 2; h2++) {
#pragma unroll
      for (int i = 0; i < DIN / 32; i++) {
        const uint4 v = *(const uint4*)(hb + (size_t)(i * 32 + sd) * NPTS + h2 * HALF + jb + sc * 8);
        *(uint4*)&sht[((size_t)bf * 2 + h2) * DIN * 72 + (i * 32 + sd) * 72 + sc * 8] = v;
      }
    }
    if (tid < 128) {
      const int jj = tid & 63;
      spnt[(bf * 2 + (tid >> 6)) * 64 + (((jj & 7) << 3) | (jj >> 3))] =
          pb[(tid >> 6) * HALF + jb + jj];
    }
  };

  stage(0, 0);
  __syncthreads();
  for (int t = 0; t < TILES; t++) {
    const int bf = t & 1;
    if (t + 1 < TILES) stage(t + 1, bf ^ 1);   // fill other buffer
#pragma unroll
    for (int s = 0; s < 2; s++) {
      short8 af;
#pragma unroll
      for (int jj = 0; jj < 8; jj++) {
        const float4 pj = spnt[(bf * 2 + hf) * 64 + ((jj << 3) | (s * 4 + q))];
        float arg = pi.w + pj.w;
        arg = fmaf(pi.x, pj.x, arg);
        arg = fmaf(pi.y, pj.y, arg);
        arg = fmaf(pi.z, pj.z, arg);
        const float w = __expf(arg);   // exp(-dist_ij)
        dacc += w;
        af[jj] = (short)f2bf(w);
      }
#pragma unroll
      for (int nt = 0; nt < NT; nt++) {
        const short8 bfr = *(const short8*)
            &sht[((size_t)bf * 2 + hf) * DIN * 72 + (nt * 16 + m) * 72 + s * 32 + q * 8];
        acc[nt] = __builtin_amdgcn_mfma_f32_16x16x32_bf16(af, bfr, acc[nt], 0, 0, 0);
      }
    }
    __syncthreads();   // staging of bf^1 done; compute of bf done
  }

  // ---- combine split-K partials in LDS (aliased over dead staging) ----
  float* snum = (float*)smem;                    // [2][32][DIN]
  float* sden = (float*)(smem + SNUM_B);         // [2][32]
  float* sinv = (float*)(smem + SNUM_B + 256);   // [32]
  float* sstat = (float*)(smem + SNUM_B + 384);  // [32][2][2]
  ushort* srow = (ushort*)(smem + OFF_SROW);     // [32][PS] bf16

  dacc += __shfl_xor(dacc, 16, 64);
  dacc += __shfl_xor(dacc, 32, 64);
  if (q == 0) sden[hf * 32 + gq * 16 + m] = dacc;
  // agg C/D layout: col = lane&15 (d), row = q*4 + reg
#pragma unroll
  for (int nt = 0; nt < NT; nt++)
#pragma unroll
    for (int r = 0; r < 4; r++)
      snum[((size_t)hf * 32 + gq * 16 + q * 4 + r) * DIN + nt * 16 + m] = acc[nt][r];
  __syncthreads();
  if (tid < 32) sinv[tid] = 1.0f / (sden[tid] + sden[32 + tid]);
  __syncthreads();
  for (int idx = tid; idx < 32 * DIN; idx += 256) {
    const int r = idx / DIN;
    srow[r * PS + (idx & (DIN - 1))] =
        f2bf((snum[idx] + snum[32 * DIN + idx]) * sinv[r]);
  }
  __syncthreads();

  // ---- dense via MFMA: C[32 x DOUT] = srow @ W; wave: rows gq*16..+15,
  //      col-tiles hf*NCOL..+NCOL-1 ----
  short8 afrag[DIN / 32];
#pragma unroll
  for (int kt = 0; kt < DIN / 32; kt++)
    afrag[kt] = *(const short8*)&srow[(gq * 16 + m) * PS + kt * 32 + q * 8];
  f32x4 oacc[NCOL];
#pragma unroll
  for (int c = 0; c < NCOL; c++)
#pragma unroll
    for (int e = 0; e < 4; e++) oacc[c][e] = 0.f;
#pragma unroll
  for (int c = 0; c < NCOL; c++) {
    const int n0 = (hf * NCOL + c) * 16;
#pragma unroll
    for (int kt = 0; kt < DIN / 32; kt++) {
      const short8 bfrag = *(const short8*)(WT + (size_t)(n0 + m) * DIN + kt * 32 + q * 8);
      oacc[c] = __builtin_amdgcn_mfma_f32_16x16x32_bf16(afrag[kt], bfrag, oacc[c], 0, 0, 0);
    }
  }

  // ---- LN stats: per-row mean/var across both col-halves via LDS ----
  float bcol[NCOL];
#pragma unroll
  for (int c = 0; c < NCOL; c++) bcol[c] = bias[(hf * NCOL + c) * 16 + m];
#pragma unroll
  for (int r = 0; r < 4; r++) {
    float m1 = 0.f, m2 = 0.f;
#pragma unroll
    for (int c = 0; c < NCOL; c++) {
      const float v = oacc[c][r] + bcol[c];
      m1 += v; m2 += v * v;
    }
#pragma unroll
    for (int off = 8; off > 0; off >>= 1) {   // reduce over 16 m-lanes
      m1 += __shfl_xor(m1, off, 64);
      m2 += __shfl_xor(m2, off, 64);
    }
    if (m == 0) {
      const int row = gq * 16 + q * 4 + r;
      sstat[(row * 2 + hf) * 2 + 0] = m1;
      sstat[(row * 2 + hf) * 2 + 1] = m2;
    }
  }
  __syncthreads();

  ushort* lt = (ushort*)smem;   // [32][DOUT], aliases dead snum
  float* sp = (float*)smem;     // [2][DOUT] for POOL
  float pacc[NCOL];
  if (POOL) {
#pragma unroll
    for (int c = 0; c < NCOL; c++) pacc[c] = 0.f;
  }
#pragma unroll
  for (int r = 0; r < 4; r++) {
    const int row = gq * 16 + q * 4 + r;
    const float m1 = sstat[(row * 2 + 0) * 2 + 0] + sstat[(row * 2 + 1) * 2 + 0];
    const float m2 = sstat[(row * 2 + 0) * 2 + 1] + sstat[(row * 2 + 1) * 2 + 1];
    const float mu = m1 / DOUT;
    const float rstd = rsqrtf(m2 / DOUT - mu * mu + 1e-6f);
    float mval = 0.f;
    if (POOL) mval = mask[(size_t)b * NPTS + i0 + row];
#pragma unroll
    for (int c = 0; c < NCOL; c++) {
      const int dco = (hf * NCOL + c) * 16 + m;
      const float v = (oacc[c][r] + bcol[c] - mu) * rstd * g[dco] + be[dco];
      const float act = v / (1.0f + __expf(-v));
      if (POOL) pacc[c] = fmaf(act, mval, pacc[c]);
      else lt[row * DOUT + dco] = f2bf(act);
    }
  }
  if (POOL) {
#pragma unroll
    for (int c = 0; c < NCOL; c++) {
      float v = pacc[c];
      v += __shfl_xor(v, 16, 64);
      v += __shfl_xor(v, 32, 64);   // sum over q -> 16 rows of this wave
      if (q == 0) sp[gq * DOUT + (hf * NCOL + c) * 16 + m] = v;
    }
    __syncthreads();
    if (tid < DOUT)
      partial[((size_t)b * (NPTS / 32) + blockIdx.x) * DOUT + tid] =
          sp[tid] + sp[DOUT + tid];
  } else {
    __syncthreads();
    if (tid < DOUT) {
      ushort tmp[32];
#pragma unroll
      for (int r = 0; r < 32; r++) tmp[r] = lt[r * DOUT + tid];
      ushort* dst = hout + ((size_t)b * DOUT + tid) * NPTS + i0;
#pragma unroll
      for (int c = 0; c < 4; c++)
        *(uint4*)(dst + c * 8) = *(uint4*)&tmp[c * 8];
    }
  }
}

// ---------------------------------------------------------------------------
// readout: reduce 64 partial rows per batch, divide by count, Dense(256->128)
// ---------------------------------------------------------------------------
__global__ __launch_bounds__(256) void readout_kernel(
    const float* __restrict__ partial, const float* __restrict__ mask,
    const float* __restrict__ Wz, const float* __restrict__ bz,
    float* __restrict__ out) {
  const int b = blockIdx.x;
  const int tid = threadIdx.x;
  const float* pb = partial + (size_t)b * (NPTS / 32) * 256;
  float s0 = 0.f, s1 = 0.f, s2 = 0.f, s3 = 0.f;
#pragma unroll 4
  for (int p = 0; p < NPTS / 32; p += 4) {
    s0 += pb[(size_t)(p + 0) * 256 + tid];
    s1 += pb[(size_t)(p + 1) * 256 + tid];
    s2 += pb[(size_t)(p + 2) * 256 + tid];
    s3 += pb[(size_t)(p + 3) * 256 + tid];
  }
  const float s = (s0 + s1) + (s2 + s3);
  const float* mb = mask + (size_t)b * NPTS;
  float c = 0.f;
  for (int n = tid; n < NPTS; n += 256) c += mb[n];
  __shared__ float red[256];
  red[tid] = c;
  __syncthreads();
  for (int off = 128; off > 0; off >>= 1) {
    if (tid < off) red[tid] += red[tid + off];
    __syncthreads();
  }
  const float cnt = fmaxf(red[0], 1.0f);
  __shared__ float gf[256];
  gf[tid] = s / cnt;
  __syncthreads();
  if (tid < LATENT) {
    float z = bz[tid];
#pragma unroll 4
    for (int d = 0; d < 256; d++) z += gf[d] * Wz[(size_t)d * LATENT + tid];
    out[(size_t)b * LATENT + tid] = z;
  }
}

// ---------------------------------------------------------------------------
extern "C" void kernel_launch(void* const* d_in, const int* in_sizes, int n_in,
                              void* d_out, int out_size, void* d_ws, size_t ws_size,
                              hipStream_t stream) {
  const float* x    = (const float*)d_in[0];
  const float* mask = (const float*)d_in[1];
  const float* W0   = (const float*)d_in[2];
  const float* b0   = (const float*)d_in[3];
  const float* g0   = (const float*)d_in[4];
  const float* be0  = (const float*)d_in[5];
  const float* W1   = (const float*)d_in[6];
  const float* b1   = (const float*)d_in[7];
  const float* g1   = (const float*)d_in[8];
  const float* be1  = (const float*)d_in[9];
  const float* W2   = (const float*)d_in[10];
  const float* b2   = (const float*)d_in[11];
  const float* g2   = (const float*)d_in[12];
  const float* be2  = (const float*)d_in[13];
  const float* Wz   = (const float*)d_in[14];
  const float* bz   = (const float*)d_in[15];
  float* out = (float*)d_out;

  // workspace layout (bytes, 16B-aligned regions)
  char* ws = (char*)d_ws;
  float4* pnt     = (float4*)(ws);             // 262144
  float*  hagg0   = (float*)(ws + 262144);     // 196608
  ushort* h1T     = (ushort*)(ws + 458752);    // 2097152
  ushort* h2T     = (ushort*)(ws + 2555904);   // 4194304
  float*  partial = (float*)(ws + 6750208);    // 524288
  ushort* WT1     = (ushort*)(ws + 7274496);   // 64*128*2  = 16384
  ushort* WT2     = (ushort*)(ws + 7290880);   // 128*256*2 = 65536
  // total ~7.4 MB

  prep_kernel<<<dim3(BATCH), dim3(256), 0, stream>>>(x, mask, pnt);
  wtrans_kernel<<<dim3(128 / 64, 64 / 64), dim3(256), 0, stream>>>(W1, WT1, 64, 128);
  wtrans_kernel<<<dim3(256 / 64, 128 / 64), dim3(256), 0, stream>>>(W2, WT2, 128, 256);

  // layer 0: h = xc (D=3), VALU fp32
  agg3_kernel<<<dim3(NPTS / 64, BATCH), dim3(256), 0, stream>>>(pnt, hagg0);
  mlp0_kernel<<<dim3(BATCH * NPTS / 16), dim3(256), 0, stream>>>(
      hagg0, W0, b0, g0, be0, h1T);

  // layer 1 (64 -> 128): fused MFMA agg + MFMA dense + LN + swish
  fused_layer<64, 128, false><<<dim3(NPTS / 32, BATCH), dim3(256), 0, stream>>>(
      pnt, h1T, WT1, b1, g1, be1, h2T, nullptr, nullptr);

  // layer 2 (128 -> 256): fused + masked-sum pooling
  fused_layer<128, 256, true><<<dim3(NPTS / 32, BATCH), dim3(256), 0, stream>>>(
      pnt, h2T, WT2, b2, g2, be2, nullptr, mask, partial);

  // readout
  readout_kernel<<<dim3(BATCH), dim3(256), 0, stream>>>(partial, mask, Wz, bz, out);
}

// Round 7
// 210.183 us; speedup vs baseline: 1.3378x; 1.0811x over previous
//
#include <hip/hip_runtime.h>
#include <hip/hip_bf16.h>

#define BATCH 8
#define NPTS 2048
#define LATENT 128

typedef __attribute__((ext_vector_type(8))) short short8;
typedef __attribute__((ext_vector_type(4))) float f32x4;

__device__ __forceinline__ ushort f2bf(float f) {
  unsigned int b = __float_as_uint(f);
  b += 0x7FFF + ((b >> 16) & 1);
  return (ushort)(b >> 16);
}

typedef unsigned int __attribute__((address_space(1))) gas_uint;
typedef unsigned int __attribute__((address_space(3))) las_uint;
__device__ __forceinline__ void gl_lds16(const void* g, void* l) {
  __builtin_amdgcn_global_load_lds((const gas_uint*)g, (las_uint*)l, 16, 0, 0);
}

// log2(e) and sqrt(2*log2(e)) — points are stored in exp2-space
#define L2E 1.4426950408889634f
#define SC2 1.6986436f

// ---------------------------------------------------------------------------
// prep: centroid + write pnt[b][n] = (SC2*xc, -|xc|^2*L2E) so that
// pi.w + pj.w + dot(pi.xyz,pj.xyz) = -L2E*dist_ij  (feed v_exp_f32 directly)
// ---------------------------------------------------------------------------
__global__ __launch_bounds__(256) void prep_kernel(const float* __restrict__ x,
    const float* __restrict__ mask, float4* __restrict__ pnt) {
  const int b = blockIdx.x;
  const int tid = threadIdx.x;
  const float* xb = x + (size_t)b * NPTS * 3;
  const float* mb = mask + (size_t)b * NPTS;
  float s0 = 0.f, s1 = 0.f, s2 = 0.f, c = 0.f;
  for (int n = tid; n < NPTS; n += 256) {
    float m = mb[n];
    s0 += xb[n * 3 + 0] * m;
    s1 += xb[n * 3 + 1] * m;
    s2 += xb[n * 3 + 2] * m;
    c += m;
  }
  __shared__ float red[4][256];
  red[0][tid] = s0; red[1][tid] = s1; red[2][tid] = s2; red[3][tid] = c;
  __syncthreads();
  for (int off = 128; off > 0; off >>= 1) {
    if (tid < off) {
      red[0][tid] += red[0][tid + off];
      red[1][tid] += red[1][tid + off];
      red[2][tid] += red[2][tid + off];
      red[3][tid] += red[3][tid + off];
    }
    __syncthreads();
  }
  const float cnt = fmaxf(red[3][0], 1.0f);
  const float c0 = red[0][0] / cnt, c1 = red[1][0] / cnt, c2 = red[2][0] / cnt;
  float4* pb = pnt + (size_t)b * NPTS;
  for (int n = tid; n < NPTS; n += 256) {
    const float a0 = xb[n * 3 + 0] - c0;
    const float a1 = xb[n * 3 + 1] - c1;
    const float a2 = xb[n * 3 + 2] - c2;
    pb[n] = make_float4(a0 * SC2, a1 * SC2, a2 * SC2,
                        -(a0 * a0 + a1 * a1 + a2 * a2) * L2E);
  }
}

// ---------------------------------------------------------------------------
// W transpose to bf16: WT[n][k] = bf16(W[k][n]); 64x64 LDS tiles.
// ---------------------------------------------------------------------------
__global__ __launch_bounds__(256) void wtrans_kernel(const float* __restrict__ W,
    ushort* __restrict__ WT, int K, int N) {
  __shared__ ushort s[64][72];
  const int tid = threadIdx.x;
  const int n0 = blockIdx.x * 64, k0 = blockIdx.y * 64;
  for (int i = tid; i < 64 * 64; i += 256) {
    const int kl = i >> 6, nl = i & 63;
    s[kl][nl] = f2bf(W[(size_t)(k0 + kl) * N + n0 + nl]);
  }
  __syncthreads();
  for (int i = tid; i < 64 * 64; i += 256) {
    const int nl = i >> 6, kl = i & 63;
    WT[(size_t)(n0 + nl) * K + k0 + kl] = s[kl][nl];
  }
}

// ---------------------------------------------------------------------------
// layer-0 aggregation (h == xc, D=3): 64 rows/block, 4-way j-split.
// pnt is in exp2-space: w = exp2(arg); xyz scaled by SC2.
// ---------------------------------------------------------------------------
__global__ __launch_bounds__(256) void agg3_kernel(const float4* __restrict__ pnt,
    float* __restrict__ hagg0) {
  const int b = blockIdx.y;
  const int i0 = blockIdx.x * 64;
  const int tid = threadIdx.x;
  const int il = tid & 63, part = tid >> 6;
  const float4* pb = pnt + (size_t)b * NPTS;
  const float4 pi = pb[i0 + il];
  float a0 = 0.f, a1 = 0.f, a2 = 0.f, dn = 0.f;
#pragma unroll 8
  for (int j = part * 512; j < part * 512 + 512; j++) {
    const float4 pj = pb[j];
    float arg = pi.w + pj.w;
    arg = fmaf(pi.x, pj.x, arg);
    arg = fmaf(pi.y, pj.y, arg);
    arg = fmaf(pi.z, pj.z, arg);
    const float w = __builtin_amdgcn_exp2f(arg);
    a0 = fmaf(w, pj.x, a0);
    a1 = fmaf(w, pj.y, a1);
    a2 = fmaf(w, pj.z, a2);
    dn += w;
  }
  __shared__ float4 sred[64][4];
  sred[il][part] = make_float4(a0, a1, a2, dn);
  __syncthreads();
  if (tid < 64) {
    const float4 r0 = sred[tid][0], r1 = sred[tid][1];
    const float4 r2 = sred[tid][2], r3 = sred[tid][3];
    const float A0 = (r0.x + r1.x) + (r2.x + r3.x);
    const float A1 = (r0.y + r1.y) + (r2.y + r3.y);
    const float A2 = (r0.z + r1.z) + (r2.z + r3.z);
    const float DN = (r0.w + r1.w) + (r2.w + r3.w);
    const float inv = 1.0f / (DN * SC2);  // undo SC2 scaling of xyz
    float* op = hagg0 + ((size_t)b * NPTS + i0 + tid) * 3;
    op[0] = A0 * inv; op[1] = A1 * inv; op[2] = A2 * inv;
  }
}

// ---------------------------------------------------------------------------
// layer-0 dense + LN + swish (DIN=3 -> DOUT=64), 16 rows/block,
// writes transposed bf16 h1T[b][d][n].
// ---------------------------------------------------------------------------
__global__ __launch_bounds__(256) void mlp0_kernel(
    const float* __restrict__ in0, const float* __restrict__ W,
    const float* __restrict__ bias, const float* __restrict__ g,
    const float* __restrict__ be, ushort* __restrict__ hout) {
  constexpr int DIN = 3, DOUT = 64;
  const int tid = threadIdx.x;
  const int wv = tid >> 6, lane = tid & 63;
  const int r0 = blockIdx.x * 16;
  __shared__ float srow[16 * DIN];
  if (tid < 16 * DIN) srow[tid] = in0[(size_t)r0 * DIN + tid];
  __syncthreads();

  float o[4];
  const float bv = bias[lane];
#pragma unroll
  for (int r = 0; r < 4; r++) o[r] = bv;
#pragma unroll
  for (int k = 0; k < DIN; k++) {
    const float wk = W[(size_t)k * DOUT + lane];
#pragma unroll
    for (int r = 0; r < 4; r++)
      o[r] = fmaf(srow[(wv * 4 + r) * DIN + k], wk, o[r]);
  }
  __shared__ ushort lt[16][DOUT];
#pragma unroll
  for (int r = 0; r < 4; r++) {
    float m1 = o[r], m2 = o[r] * o[r];
#pragma unroll
    for (int off = 32; off > 0; off >>= 1) {
      m1 += __shfl_xor(m1, off, 64);
      m2 += __shfl_xor(m2, off, 64);
    }
    const float mu = m1 / DOUT;
    const float var = m2 / DOUT - mu * mu;
    const float rstd = rsqrtf(var + 1e-6f);
    const float v = (o[r] - mu) * rstd * g[lane] + be[lane];
    const float act = v / (1.0f + __expf(-v));
    lt[wv * 4 + r][lane] = f2bf(act);
  }
  __syncthreads();
  if (tid < DOUT) {
    ushort tmp[16];
#pragma unroll
    for (int r = 0; r < 16; r++) tmp[r] = lt[r][tid];
    const int bb = r0 / NPTS;
    const int nn = r0 % NPTS;
    ushort* dst = hout + ((size_t)bb * DOUT + tid) * NPTS + nn;
    *(uint4*)dst = *(uint4*)&tmp[0];
    *(uint4*)(dst + 8) = *(uint4*)&tmp[8];
  }
}

// ---------------------------------------------------------------------------
// FUSED layer v4:
//  - agg via MFMA; each wave owns ALL 32 block rows (2 A-frags) and a j
//    quarter -> every B/pj LDS read feeds 2 MFMAs (halved LDS reads).
//  - h tiles staged by global_load_lds (DMA, no ds_write issues), pitch 64
//    with XOR chunk swizzle (pos = chunk ^ (row&7)) for bank balance.
//  - dense epilogue via MFMA on bf16 WT, LN + swish fused;
//    POOL=true emits mask-weighted column-sum partials.
// ---------------------------------------------------------------------------
template <int DIN, int DOUT, bool POOL, int MINW>
__global__ __launch_bounds__(256, MINW) void fused_layer(
    const float4* __restrict__ pnt, const ushort* __restrict__ hT,
    const ushort* __restrict__ WT, const float* __restrict__ bias,
    const float* __restrict__ g, const float* __restrict__ be,
    ushort* __restrict__ hout, const float* __restrict__ mask,
    float* __restrict__ partial) {
  constexpr int NT = DIN / 16;
  constexpr int HALF = NPTS / 2;
  constexpr int TILES = HALF / 64;      // 16
  constexpr int NCOL = DOUT / 32;       // dense col-tiles per wave
  constexpr int PS = DIN + 8;           // srow pitch (ushorts)
  constexpr int PN = DIN + 4;           // snum pitch (floats)
  constexpr int SHT_B = 2 * 2 * DIN * 64 * 2;   // [buf][half][DIN][64] ushort
  constexpr int SPNT_B = 2 * 2 * 64 * 16;       // [buf][half][64] float4
  constexpr int LOOP_B = SHT_B + SPNT_B;
  constexpr int SNUM_B = 4 * 32 * PN * 4;       // [wave][row][d]
  constexpr int OFF_SDEN = SNUM_B;              // [4][32] float
  constexpr int OFF_SINV = OFF_SDEN + 512;      // [32] float
  constexpr int OFF_SSTAT = OFF_SINV + 128;     // [32][2][2] float
  constexpr int OFF_SROW = OFF_SSTAT + 512;     // [32][PS] ushort
  constexpr int EPI_B = OFF_SROW + 32 * PS * 2;
  constexpr int SMEM_B = LOOP_B > EPI_B ? LOOP_B : EPI_B;
  __shared__ __align__(16) char smem[SMEM_B];
  ushort* sht = (ushort*)smem;
  float4* spnt = (float4*)(smem + SHT_B);

  const int b = blockIdx.y;
  const int i0 = blockIdx.x * 32;
  const int tid = threadIdx.x;
  const int wv = tid >> 6, lane = tid & 63;
  const int h = wv >> 1;     // j half
  const int u = wv & 1;      // 32-j sub-tile within the 64-j tile
  const int m = lane & 15, q = lane >> 4;
  const float4* pb = pnt + (size_t)b * NPTS;
  const ushort* hb = hT + (size_t)b * DIN * NPTS;

  const float4 pi0 = pb[i0 + m];        // A-rows 0..15
  const float4 pi1 = pb[i0 + 16 + m];   // A-rows 16..31

  f32x4 acc0[NT], acc1[NT];
#pragma unroll
  for (int nt = 0; nt < NT; nt++)
#pragma unroll
    for (int e = 0; e < 4; e++) { acc0[nt][e] = 0.f; acc1[nt][e] = 0.f; }
  float dacc0 = 0.f, dacc1 = 0.f;

  constexpr int NCH = (2 * DIN / 8) / 4;   // sht DMA issues per wave
  const int srow8 = lane >> 3;             // row within octet
  const int scsrc = (lane & 7) ^ srow8;    // XOR-swizzled source chunk
  const int jsw = ((lane & 7) << 3) | (lane >> 3);  // spnt swizzle (involution)

  auto stage = [&](int t, int bf) {
    const int jb = t * 64;
#pragma unroll
    for (int i = 0; i < NCH; i++) {
      const int idx = wv * NCH + i;
      const int h2 = idx / (2 * NCH);
      const int oct = idx % (2 * NCH);
      const int row = oct * 8 + srow8;
      gl_lds16(hb + (size_t)row * NPTS + h2 * HALF + jb + scsrc * 8,
               sht + ((size_t)(bf * 2 + h2) * DIN + oct * 8) * 64);
    }
    if (wv == 0) {
#pragma unroll
      for (int h2 = 0; h2 < 2; h2++)
        gl_lds16(pb + h2 * HALF + jb + jsw, spnt + (bf * 2 + h2) * 64);
    }
  };

  stage(0, 0);
  __syncthreads();
  for (int t = 0; t < TILES; t++) {
    const int bf = t & 1;
    if (t + 1 < TILES) stage(t + 1, bf ^ 1);   // DMA into other buffer
    short8 af0, af1;
#pragma unroll
    for (int jj = 0; jj < 8; jj++) {
      const float4 pj = spnt[(bf * 2 + h) * 64 + ((jj << 3) | (u * 4 + q))];
      float a0 = pi0.w + pj.w;
      a0 = fmaf(pi0.x, pj.x, a0);
      a0 = fmaf(pi0.y, pj.y, a0);
      a0 = fmaf(pi0.z, pj.z, a0);
      float a1 = pi1.w + pj.w;
      a1 = fmaf(pi1.x, pj.x, a1);
      a1 = fmaf(pi1.y, pj.y, a1);
      a1 = fmaf(pi1.z, pj.z, a1);
      const float w0 = __builtin_amdgcn_exp2f(a0);   // exp(-dist)
      const float w1 = __builtin_amdgcn_exp2f(a1);
      dacc0 += w0; dacc1 += w1;
      af0[jj] = (short)f2bf(w0);
      af1[jj] = (short)f2bf(w1);
    }
#pragma unroll
    for (int nt = 0; nt < NT; nt++) {
      const int d = nt * 16 + m;
      const short8 bfr = *(const short8*)
          &sht[((size_t)(bf * 2 + h) * DIN + d) * 64 + (((u * 4 + q) ^ (m & 7)) << 3)];
      acc0[nt] = __builtin_amdgcn_mfma_f32_16x16x32_bf16(af0, bfr, acc0[nt], 0, 0, 0);
      acc1[nt] = __builtin_amdgcn_mfma_f32_16x16x32_bf16(af1, bfr, acc1[nt], 0, 0, 0);
    }
    __syncthreads();
  }

  // ---- combine the 4 j-quarters in LDS (aliased over dead staging) ----
  float* snum = (float*)smem;
  float* sden = (float*)(smem + OFF_SDEN);
  float* sinv = (float*)(smem + OFF_SINV);
  float* sstat = (float*)(smem + OFF_SSTAT);
  ushort* srow = (ushort*)(smem + OFF_SROW);

  dacc0 += __shfl_xor(dacc0, 16, 64);
  dacc0 += __shfl_xor(dacc0, 32, 64);
  dacc1 += __shfl_xor(dacc1, 16, 64);
  dacc1 += __shfl_xor(dacc1, 32, 64);
  if (q == 0) {
    sden[wv * 32 + m] = dacc0;
    sden[wv * 32 + 16 + m] = dacc1;
  }
  // agg C/D layout: col = lane&15 (d), row = q*4 + reg
#pragma unroll
  for (int nt = 0; nt < NT; nt++)
#pragma unroll
    for (int r = 0; r < 4; r++) {
      snum[(wv * 32 + q * 4 + r) * PN + nt * 16 + m] = acc0[nt][r];
      snum[(wv * 32 + 16 + q * 4 + r) * PN + nt * 16 + m] = acc1[nt][r];
    }
  __syncthreads();
  if (tid < 32)
    sinv[tid] = 1.0f / ((sden[tid] + sden[32 + tid]) + (sden[64 + tid] + sden[96 + tid]));
  __syncthreads();
  for (int idx = tid; idx < 32 * DIN; idx += 256) {
    const int r = idx / DIN, c = idx % DIN;
    const float s = ((snum[r * PN + c] + snum[32 * PN + r * PN + c]) +
                     (snum[64 * PN + r * PN + c] + snum[96 * PN + r * PN + c])) * sinv[r];
    srow[r * PS + c] = f2bf(s);
  }
  __syncthreads();

  // ---- dense via MFMA: rows (wv&1)*16.., col-tiles (wv>>1)*NCOL.. ----
  const int rg2 = wv & 1, ch = wv >> 1;
  short8 afrag[DIN / 32];
#pragma unroll
  for (int kt = 0; kt < DIN / 32; kt++)
    afrag[kt] = *(const short8*)&srow[(rg2 * 16 + m) * PS + kt * 32 + q * 8];
  f32x4 oacc[NCOL];
#pragma unroll
  for (int c = 0; c < NCOL; c++)
#pragma unroll
    for (int e = 0; e < 4; e++) oacc[c][e] = 0.f;
#pragma unroll
  for (int c = 0; c < NCOL; c++) {
    const int n0 = (ch * NCOL + c) * 16;
#pragma unroll
    for (int kt = 0; kt < DIN / 32; kt++) {
      const short8 bfrag = *(const short8*)(WT + (size_t)(n0 + m) * DIN + kt * 32 + q * 8);
      oacc[c] = __builtin_amdgcn_mfma_f32_16x16x32_bf16(afrag[kt], bfrag, oacc[c], 0, 0, 0);
    }
  }

  // ---- LN stats across both col-halves via LDS ----
  float bcol[NCOL];
#pragma unroll
  for (int c = 0; c < NCOL; c++) bcol[c] = bias[(ch * NCOL + c) * 16 + m];
#pragma unroll
  for (int r = 0; r < 4; r++) {
    float m1 = 0.f, m2 = 0.f;
#pragma unroll
    for (int c = 0; c < NCOL; c++) {
      const float v = oacc[c][r] + bcol[c];
      m1 += v; m2 += v * v;
    }
#pragma unroll
    for (int off = 8; off > 0; off >>= 1) {
      m1 += __shfl_xor(m1, off, 64);
      m2 += __shfl_xor(m2, off, 64);
    }
    if (m == 0) {
      const int row = rg2 * 16 + q * 4 + r;
      sstat[(row * 2 + ch) * 2 + 0] = m1;
      sstat[(row * 2 + ch) * 2 + 1] = m2;
    }
  }
  __syncthreads();

  ushort* lt = (ushort*)smem;   // [32][DOUT], aliases dead snum
  float* sp = (float*)smem;     // [2][DOUT] for POOL
  float pacc[NCOL];
  if (POOL) {
#pragma unroll
    for (int c = 0; c < NCOL; c++) pacc[c] = 0.f;
  }
#pragma unroll
  for (int r = 0; r < 4; r++) {
    const int row = rg2 * 16 + q * 4 + r;
    const float m1 = sstat[(row * 2 + 0) * 2 + 0] + sstat[(row * 2 + 1) * 2 + 0];
    const float m2 = sstat[(row * 2 + 0) * 2 + 1] + sstat[(row * 2 + 1) * 2 + 1];
    const float mu = m1 / DOUT;
    const float rstd = rsqrtf(m2 / DOUT - mu * mu + 1e-6f);
    float mval = 0.f;
    if (POOL) mval = mask[(size_t)b * NPTS + i0 + row];
#pragma unroll
    for (int c = 0; c < NCOL; c++) {
      const int dco = (ch * NCOL + c) * 16 + m;
      const float v = (oacc[c][r] + bcol[c] - mu) * rstd * g[dco] + be[dco];
      const float act = v / (1.0f + __expf(-v));
      if (POOL) pacc[c] = fmaf(act, mval, pacc[c]);
      else lt[row * DOUT + dco] = f2bf(act);
    }
  }
  if (POOL) {
#pragma unroll
    for (int c = 0; c < NCOL; c++) {
      float v = pacc[c];
      v += __shfl_xor(v, 16, 64);
      v += __shfl_xor(v, 32, 64);   // sum over q -> this wave's 16 rows
      if (q == 0) sp[rg2 * DOUT + (ch * NCOL + c) * 16 + m] = v;
    }
    __syncthreads();
    if (tid < DOUT)
      partial[((size_t)b * (NPTS / 32) + blockIdx.x) * DOUT + tid] =
          sp[tid] + sp[DOUT + tid];
  } else {
    __syncthreads();
    if (tid < DOUT) {
      ushort tmp[32];
#pragma unroll
      for (int r = 0; r < 32; r++) tmp[r] = lt[r * DOUT + tid];
      ushort* dst = hout + ((size_t)b * DOUT + tid) * NPTS + i0;
#pragma unroll
      for (int c = 0; c < 4; c++)
        *(uint4*)(dst + c * 8) = *(uint4*)&tmp[c * 8];
    }
  }
}

// ---------------------------------------------------------------------------
// readout: reduce 64 partial rows per batch, divide by count, Dense(256->128)
// ---------------------------------------------------------------------------
__global__ __launch_bounds__(256) void readout_kernel(
    const float* __restrict__ partial, const float* __restrict__ mask,
    const float* __restrict__ Wz, const float* __restrict__ bz,
    float* __restrict__ out) {
  const int b = blockIdx.x;
  const int tid = threadIdx.x;
  const float* pb = partial + (size_t)b * (NPTS / 32) * 256;
  float s0 = 0.f, s1 = 0.f, s2 = 0.f, s3 = 0.f;
#pragma unroll 4
  for (int p = 0; p < NPTS / 32; p += 4) {
    s0 += pb[(size_t)(p + 0) * 256 + tid];
    s1 += pb[(size_t)(p + 1) * 256 + tid];
    s2 += pb[(size_t)(p + 2) * 256 + tid];
    s3 += pb[(size_t)(p + 3) * 256 + tid];
  }
  const float s = (s0 + s1) + (s2 + s3);
  const float* mb = mask + (size_t)b * NPTS;
  float c = 0.f;
  for (int n = tid; n < NPTS; n += 256) c += mb[n];
  __shared__ float red[256];
  red[tid] = c;
  __syncthreads();
  for (int off = 128; off > 0; off >>= 1) {
    if (tid < off) red[tid] += red[tid + off];
    __syncthreads();
  }
  const float cnt = fmaxf(red[0], 1.0f);
  __shared__ float gf[256];
  gf[tid] = s / cnt;
  __syncthreads();
  if (tid < LATENT) {
    float z = bz[tid];
#pragma unroll 4
    for (int d = 0; d < 256; d++) z += gf[d] * Wz[(size_t)d * LATENT + tid];
    out[(size_t)b * LATENT + tid] = z;
  }
}

// ---------------------------------------------------------------------------
extern "C" void kernel_launch(void* const* d_in, const int* in_sizes, int n_in,
                              void* d_out, int out_size, void* d_ws, size_t ws_size,
                              hipStream_t stream) {
  const float* x    = (const float*)d_in[0];
  const float* mask = (const float*)d_in[1];
  const float* W0   = (const float*)d_in[2];
  const float* b0   = (const float*)d_in[3];
  const float* g0   = (const float*)d_in[4];
  const float* be0  = (const float*)d_in[5];
  const float* W1   = (const float*)d_in[6];
  const float* b1   = (const float*)d_in[7];
  const float* g1   = (const float*)d_in[8];
  const float* be1  = (const float*)d_in[9];
  const float* W2   = (const float*)d_in[10];
  const float* b2   = (const float*)d_in[11];
  const float* g2   = (const float*)d_in[12];
  const float* be2  = (const float*)d_in[13];
  const float* Wz   = (const float*)d_in[14];
  const float* bz   = (const float*)d_in[15];
  float* out = (float*)d_out;

  // workspace layout (bytes, 16B-aligned regions)
  char* ws = (char*)d_ws;
  float4* pnt     = (float4*)(ws);             // 262144
  float*  hagg0   = (float*)(ws + 262144);     // 196608
  ushort* h1T     = (ushort*)(ws + 458752);    // 2097152
  ushort* h2T     = (ushort*)(ws + 2555904);   // 4194304
  float*  partial = (float*)(ws + 6750208);    // 524288
  ushort* WT1     = (ushort*)(ws + 7274496);   // 16384
  ushort* WT2     = (ushort*)(ws + 7290880);   // 65536
  // total ~7.4 MB

  prep_kernel<<<dim3(BATCH), dim3(256), 0, stream>>>(x, mask, pnt);
  wtrans_kernel<<<dim3(128 / 64, 64 / 64), dim3(256), 0, stream>>>(W1, WT1, 64, 128);
  wtrans_kernel<<<dim3(256 / 64, 128 / 64), dim3(256), 0, stream>>>(W2, WT2, 128, 256);

  // layer 0: h = xc (D=3), VALU fp32
  agg3_kernel<<<dim3(NPTS / 64, BATCH), dim3(256), 0, stream>>>(pnt, hagg0);
  mlp0_kernel<<<dim3(BATCH * NPTS / 16), dim3(256), 0, stream>>>(
      hagg0, W0, b0, g0, be0, h1T);

  // layer 1 (64 -> 128): fused MFMA agg + MFMA dense + LN + swish
  fused_layer<64, 128, false, 3><<<dim3(NPTS / 32, BATCH), dim3(256), 0, stream>>>(
      pnt, h1T, WT1, b1, g1, be1, h2T, nullptr, nullptr);

  // layer 2 (128 -> 256): fused + masked-sum pooling
  fused_layer<128, 256, true, 2><<<dim3(NPTS / 32, BATCH), dim3(256), 0, stream>>>(
      pnt, h2T, WT2, b2, g2, be2, nullptr, mask, partial);

  // readout
  readout_kernel<<<dim3(BATCH), dim3(256), 0, stream>>>(partial, mask, Wz, bz, out);
}

// Round 8
// 196.808 us; speedup vs baseline: 1.4287x; 1.0680x over previous
//
#include <hip/hip_runtime.h>
#include <hip/hip_bf16.h>

#define BATCH 8
#define NPTS 2048
#define LATENT 128

typedef __attribute__((ext_vector_type(8))) short short8;
typedef __attribute__((ext_vector_type(4))) float f32x4;

__device__ __forceinline__ ushort f2bf(float f) {
  unsigned int b = __float_as_uint(f);
  b += 0x7FFF + ((b >> 16) & 1);
  return (ushort)(b >> 16);
}

typedef unsigned int __attribute__((address_space(1))) gas_uint;
typedef unsigned int __attribute__((address_space(3))) las_uint;
__device__ __forceinline__ void gl_lds16(const void* g, void* l) {
  __builtin_amdgcn_global_load_lds((const gas_uint*)g, (las_uint*)l, 16, 0, 0);
}

// log2(e) and sqrt(2*log2(e)) — points are stored in exp2-space
#define L2E 1.4426950408889634f
#define SC2 1.6986436f

// ---------------------------------------------------------------------------
// setup: blockIdx 0..7 = prep (centroid + pnt), 8..9 = WT1, 10..17 = WT2.
// pnt[b][n] = (SC2*xc, -|xc|^2*L2E): pi.w+pj.w+dot(pi.xyz,pj.xyz) = -L2E*dist.
// WT[n][k] = bf16(W[k][n]).
// ---------------------------------------------------------------------------
__device__ __forceinline__ void wtrans_tile(const float* __restrict__ W,
    ushort* __restrict__ WT, int K, int N, int n0, int k0, int tid) {
  __shared__ ushort s[64][72];
  for (int i = tid; i < 64 * 64; i += 256) {
    const int kl = i >> 6, nl = i & 63;
    s[kl][nl] = f2bf(W[(size_t)(k0 + kl) * N + n0 + nl]);
  }
  __syncthreads();
  for (int i = tid; i < 64 * 64; i += 256) {
    const int nl = i >> 6, kl = i & 63;
    WT[(size_t)(n0 + nl) * K + k0 + kl] = s[kl][nl];
  }
}

__global__ __launch_bounds__(256) void setup_kernel(const float* __restrict__ x,
    const float* __restrict__ mask, float4* __restrict__ pnt,
    const float* __restrict__ W1, ushort* __restrict__ WT1,
    const float* __restrict__ W2, ushort* __restrict__ WT2) {
  const int bid = blockIdx.x;
  const int tid = threadIdx.x;
  if (bid >= 8) {
    if (bid < 10) wtrans_tile(W1, WT1, 64, 128, (bid - 8) * 64, 0, tid);
    else {
      const int idx = bid - 10;
      wtrans_tile(W2, WT2, 128, 256, (idx & 3) * 64, (idx >> 2) * 64, tid);
    }
    return;
  }
  const int b = bid;
  const float* xb = x + (size_t)b * NPTS * 3;
  const float* mb = mask + (size_t)b * NPTS;
  float s0 = 0.f, s1 = 0.f, s2 = 0.f, c = 0.f;
  for (int n = tid; n < NPTS; n += 256) {
    float m = mb[n];
    s0 += xb[n * 3 + 0] * m;
    s1 += xb[n * 3 + 1] * m;
    s2 += xb[n * 3 + 2] * m;
    c += m;
  }
  __shared__ float red[4][256];
  red[0][tid] = s0; red[1][tid] = s1; red[2][tid] = s2; red[3][tid] = c;
  __syncthreads();
  for (int off = 128; off > 0; off >>= 1) {
    if (tid < off) {
      red[0][tid] += red[0][tid + off];
      red[1][tid] += red[1][tid + off];
      red[2][tid] += red[2][tid + off];
      red[3][tid] += red[3][tid + off];
    }
    __syncthreads();
  }
  const float cnt = fmaxf(red[3][0], 1.0f);
  const float c0 = red[0][0] / cnt, c1 = red[1][0] / cnt, c2 = red[2][0] / cnt;
  float4* pb = pnt + (size_t)b * NPTS;
  for (int n = tid; n < NPTS; n += 256) {
    const float a0 = xb[n * 3 + 0] - c0;
    const float a1 = xb[n * 3 + 1] - c1;
    const float a2 = xb[n * 3 + 2] - c2;
    pb[n] = make_float4(a0 * SC2, a1 * SC2, a2 * SC2,
                        -(a0 * a0 + a1 * a1 + a2 * a2) * L2E);
  }
}

// ---------------------------------------------------------------------------
// layer 0 fused: aggregation (D=3, VALU, 8-way j-split) + dense 3->64 +
// LN + swish + transposed bf16 write h1T[b][d][n]. 64 rows/block, 512 thr.
// ---------------------------------------------------------------------------
__global__ __launch_bounds__(512) void layer0_kernel(
    const float4* __restrict__ pnt, const float* __restrict__ W,
    const float* __restrict__ bias, const float* __restrict__ g,
    const float* __restrict__ be, ushort* __restrict__ hout) {
  const int b = blockIdx.y;
  const int i0 = blockIdx.x * 64;
  const int tid = threadIdx.x;
  const int il = tid & 63, part = tid >> 6;   // 8 j-parts
  const float4* pb = pnt + (size_t)b * NPTS;
  const float4 pi = pb[i0 + il];
  float a0 = 0.f, a1 = 0.f, a2 = 0.f, dn = 0.f;
#pragma unroll 8
  for (int j = part * 256; j < part * 256 + 256; j++) {
    const float4 pj = pb[j];
    float arg = pi.w + pj.w;
    arg = fmaf(pi.x, pj.x, arg);
    arg = fmaf(pi.y, pj.y, arg);
    arg = fmaf(pi.z, pj.z, arg);
    const float w = __builtin_amdgcn_exp2f(arg);
    a0 = fmaf(w, pj.x, a0);
    a1 = fmaf(w, pj.y, a1);
    a2 = fmaf(w, pj.z, a2);
    dn += w;
  }
  __shared__ float4 sred[8][64];
  __shared__ float srow[64 * 3];
  __shared__ ushort lt[64][64];
  sred[part][il] = make_float4(a0, a1, a2, dn);
  __syncthreads();
  if (tid < 64) {
    float A0 = 0.f, A1 = 0.f, A2 = 0.f, DN = 0.f;
#pragma unroll
    for (int p = 0; p < 8; p++) {
      const float4 r = sred[p][tid];
      A0 += r.x; A1 += r.y; A2 += r.z; DN += r.w;
    }
    const float inv = 1.0f / (DN * SC2);   // undo SC2 scaling of xyz
    srow[tid * 3 + 0] = A0 * inv;
    srow[tid * 3 + 1] = A1 * inv;
    srow[tid * 3 + 2] = A2 * inv;
  }
  __syncthreads();
  const int wv = tid >> 6, lane = tid & 63;
  const float w0c = W[lane], w1c = W[64 + lane], w2c = W[128 + lane];
  const float gv = g[lane], bev = be[lane], bv = bias[lane];
#pragma unroll
  for (int r = 0; r < 8; r++) {
    const int row = wv * 8 + r;
    float o = bv;
    o = fmaf(srow[row * 3 + 0], w0c, o);
    o = fmaf(srow[row * 3 + 1], w1c, o);
    o = fmaf(srow[row * 3 + 2], w2c, o);
    float m1 = o, m2 = o * o;
#pragma unroll
    for (int off = 32; off > 0; off >>= 1) {
      m1 += __shfl_xor(m1, off, 64);
      m2 += __shfl_xor(m2, off, 64);
    }
    const float mu = m1 / 64.f;
    const float rstd = rsqrtf(m2 / 64.f - mu * mu + 1e-6f);
    const float v = (o - mu) * rstd * gv + bev;
    const float act = v / (1.0f + __expf(-v));
    lt[row][lane] = f2bf(act);
  }
  __syncthreads();
  if (tid < 64) {
    ushort tmp[64];
#pragma unroll
    for (int r = 0; r < 64; r++) tmp[r] = lt[r][tid];
    ushort* dst = hout + ((size_t)b * 64 + tid) * NPTS + i0;
#pragma unroll
    for (int c = 0; c < 8; c++)
      *(uint4*)(dst + c * 8) = *(uint4*)&tmp[c * 8];
  }
}

// ---------------------------------------------------------------------------
// FUSED layer v5: 64 rows/block, 512 threads (8 waves = row-half x j-quarter)
// => one staging stream per CU (halved DMA), 2-A-frag amortization kept.
// agg via MFMA (w generated in regs, exp2-space), h staged by global_load_lds
// with XOR chunk swizzle; 1-slot 4-phase split-K combine; dense epilogue via
// MFMA on bf16 WT; LN + swish; POOL emits mask-weighted column partials.
// ---------------------------------------------------------------------------
template <int DIN, int DOUT, bool POOL>
__global__ __launch_bounds__(512, 2) void fused_layer(
    const float4* __restrict__ pnt, const ushort* __restrict__ hT,
    const ushort* __restrict__ WT, const float* __restrict__ bias,
    const float* __restrict__ g, const float* __restrict__ be,
    ushort* __restrict__ hout, const float* __restrict__ mask,
    float* __restrict__ partial) {
  constexpr int NT = DIN / 16;
  constexpr int HALF = NPTS / 2;
  constexpr int TILES = HALF / 64;      // 16
  constexpr int NCOL = DOUT / 32;       // dense col-tiles per wave
  constexpr int PS = DIN + 8;           // srow pitch (ushorts)
  constexpr int PN = DIN + 4;           // snum pitch (floats)
  constexpr int SHT_B = 2 * 2 * DIN * 64 * 2;   // [buf][half][DIN][64] ushort
  constexpr int SPNT_B = 2 * 2 * 64 * 16;       // [buf][half][64] float4
  constexpr int LOOP_B = SHT_B + SPNT_B;
  constexpr int SNUM_B = 64 * PN * 4;           // [row][d] single slot
  constexpr int OFF_SROW = SNUM_B;              // [64][PS] ushort
  constexpr int OFF_SDEN = OFF_SROW + 64 * PS * 2;  // [64] float
  constexpr int OFF_SINV = OFF_SDEN + 256;      // [64] float
  constexpr int OFF_SSTAT = OFF_SINV + 256;     // [64][2][2] float
  constexpr int EPI_B = OFF_SSTAT + 1024;
  constexpr int SMEM_B = LOOP_B > EPI_B ? LOOP_B : EPI_B;
  __shared__ __align__(16) char smem[SMEM_B];
  ushort* sht = (ushort*)smem;
  float4* spnt = (float4*)(smem + SHT_B);

  const int b = blockIdx.y;
  const int i0 = blockIdx.x * 64;
  const int tid = threadIdx.x;
  const int wv = tid >> 6, lane = tid & 63;
  const int h = (wv >> 1) & 1;   // j half
  const int u = wv & 1;          // 32-j sub-tile
  const int rg = wv >> 2;        // row half (32 rows)
  const int m = lane & 15, q = lane >> 4;
  const float4* pb = pnt + (size_t)b * NPTS;
  const ushort* hb = hT + (size_t)b * DIN * NPTS;

  const float4 pi0 = pb[i0 + rg * 32 + m];        // A-rows +0..15
  const float4 pi1 = pb[i0 + rg * 32 + 16 + m];   // A-rows +16..31

  f32x4 acc0[NT], acc1[NT];
#pragma unroll
  for (int nt = 0; nt < NT; nt++)
#pragma unroll
    for (int e = 0; e < 4; e++) { acc0[nt][e] = 0.f; acc1[nt][e] = 0.f; }
  float dacc0 = 0.f, dacc1 = 0.f;

  constexpr int NCH = DIN / 32;            // sht DMA issues per wave
  const int srow8 = lane >> 3;
  const int scsrc = (lane & 7) ^ srow8;    // XOR-swizzled source chunk
  const int jsw = ((lane & 7) << 3) | (lane >> 3);  // spnt swizzle (involution)

  auto stage = [&](int t, int bf) {
    const int jb = t * 64;
#pragma unroll
    for (int i = 0; i < NCH; i++) {
      const int idx = wv * NCH + i;
      const int h2 = idx / (DIN / 8);
      const int oct = idx % (DIN / 8);
      const int row = oct * 8 + srow8;
      gl_lds16(hb + (size_t)row * NPTS + h2 * HALF + jb + scsrc * 8,
               sht + ((size_t)(bf * 2 + h2) * DIN + oct * 8) * 64);
    }
    if (wv == 0) {
#pragma unroll
      for (int h2 = 0; h2 < 2; h2++)
        gl_lds16(pb + h2 * HALF + jb + jsw, spnt + (bf * 2 + h2) * 64);
    }
  };

  stage(0, 0);
  __syncthreads();
  for (int t = 0; t < TILES; t++) {
    const int bf = t & 1;
    if (t + 1 < TILES) stage(t + 1, bf ^ 1);   // DMA into other buffer
    short8 af0, af1;
#pragma unroll
    for (int jj = 0; jj < 8; jj++) {
      const float4 pj = spnt[(bf * 2 + h) * 64 + ((jj << 3) | (u * 4 + q))];
      float a0 = pi0.w + pj.w;
      a0 = fmaf(pi0.x, pj.x, a0);
      a0 = fmaf(pi0.y, pj.y, a0);
      a0 = fmaf(pi0.z, pj.z, a0);
      float a1 = pi1.w + pj.w;
      a1 = fmaf(pi1.x, pj.x, a1);
      a1 = fmaf(pi1.y, pj.y, a1);
      a1 = fmaf(pi1.z, pj.z, a1);
      const float w0 = __builtin_amdgcn_exp2f(a0);   // exp(-dist)
      const float w1 = __builtin_amdgcn_exp2f(a1);
      dacc0 += w0; dacc1 += w1;
      af0[jj] = (short)f2bf(w0);
      af1[jj] = (short)f2bf(w1);
    }
#pragma unroll
    for (int nt = 0; nt < NT; nt++) {
      const int d = nt * 16 + m;
      const short8 bfr = *(const short8*)
          &sht[((size_t)(bf * 2 + h) * DIN + d) * 64 + (((u * 4 + q) ^ (m & 7)) << 3)];
      acc0[nt] = __builtin_amdgcn_mfma_f32_16x16x32_bf16(af0, bfr, acc0[nt], 0, 0, 0);
      acc1[nt] = __builtin_amdgcn_mfma_f32_16x16x32_bf16(af1, bfr, acc1[nt], 0, 0, 0);
    }
    __syncthreads();
  }

  // ---- 1-slot 4-phase split-K combine in LDS (aliased over dead staging) --
  float* snum = (float*)smem;                    // [64][PN]
  ushort* srow = (ushort*)(smem + OFF_SROW);     // [64][PS]
  float* sden = (float*)(smem + OFF_SDEN);
  float* sinv = (float*)(smem + OFF_SINV);
  float* sstat = (float*)(smem + OFF_SSTAT);

  dacc0 += __shfl_xor(dacc0, 16, 64);
  dacc0 += __shfl_xor(dacc0, 32, 64);
  dacc1 += __shfl_xor(dacc1, 16, 64);
  dacc1 += __shfl_xor(dacc1, 32, 64);
  const int quarter = wv & 3;
  for (int p = 0; p < 4; p++) {
    if (quarter == p) {
      if (p == 0) {
#pragma unroll
        for (int nt = 0; nt < NT; nt++)
#pragma unroll
          for (int r = 0; r < 4; r++) {
            snum[(rg * 32 + q * 4 + r) * PN + nt * 16 + m] = acc0[nt][r];
            snum[(rg * 32 + 16 + q * 4 + r) * PN + nt * 16 + m] = acc1[nt][r];
          }
        if (q == 0) {
          sden[rg * 32 + m] = dacc0;
          sden[rg * 32 + 16 + m] = dacc1;
        }
      } else {
#pragma unroll
        for (int nt = 0; nt < NT; nt++)
#pragma unroll
          for (int r = 0; r < 4; r++) {
            snum[(rg * 32 + q * 4 + r) * PN + nt * 16 + m] += acc0[nt][r];
            snum[(rg * 32 + 16 + q * 4 + r) * PN + nt * 16 + m] += acc1[nt][r];
          }
        if (q == 0) {
          sden[rg * 32 + m] += dacc0;
          sden[rg * 32 + 16 + m] += dacc1;
        }
      }
    }
    __syncthreads();
  }
  if (tid < 64) sinv[tid] = 1.0f / sden[tid];
  __syncthreads();
  for (int idx = tid; idx < 64 * DIN; idx += 512) {
    const int r = idx / DIN, c = idx & (DIN - 1);
    srow[r * PS + c] = f2bf(snum[r * PN + c] * sinv[r]);
  }
  __syncthreads();

  // ---- dense via MFMA: rows (wv>>1)*16.., col-half (wv&1) ----
  const int rg2 = wv >> 1, ch = wv & 1;
  short8 afrag[DIN / 32];
#pragma unroll
  for (int kt = 0; kt < DIN / 32; kt++)
    afrag[kt] = *(const short8*)&srow[(rg2 * 16 + m) * PS + kt * 32 + q * 8];
  f32x4 oacc[NCOL];
#pragma unroll
  for (int c = 0; c < NCOL; c++)
#pragma unroll
    for (int e = 0; e < 4; e++) oacc[c][e] = 0.f;
#pragma unroll
  for (int c = 0; c < NCOL; c++) {
    const int n0 = (ch * NCOL + c) * 16;
#pragma unroll
    for (int kt = 0; kt < DIN / 32; kt++) {
      const short8 bfrag = *(const short8*)(WT + (size_t)(n0 + m) * DIN + kt * 32 + q * 8);
      oacc[c] = __builtin_amdgcn_mfma_f32_16x16x32_bf16(afrag[kt], bfrag, oacc[c], 0, 0, 0);
    }
  }

  // ---- LN stats across both col-halves via LDS ----
  float bcol[NCOL];
#pragma unroll
  for (int c = 0; c < NCOL; c++) bcol[c] = bias[(ch * NCOL + c) * 16 + m];
#pragma unroll
  for (int r = 0; r < 4; r++) {
    float m1 = 0.f, m2 = 0.f;
#pragma unroll
    for (int c = 0; c < NCOL; c++) {
      const float v = oacc[c][r] + bcol[c];
      m1 += v; m2 += v * v;
    }
#pragma unroll
    for (int off = 8; off > 0; off >>= 1) {
      m1 += __shfl_xor(m1, off, 64);
      m2 += __shfl_xor(m2, off, 64);
    }
    if (m == 0) {
      const int row = rg2 * 16 + q * 4 + r;
      sstat[(row * 2 + ch) * 2 + 0] = m1;
      sstat[(row * 2 + ch) * 2 + 1] = m2;
    }
  }
  __syncthreads();

  ushort* lt = (ushort*)smem;   // [64][DOUT], aliases dead snum (TOUT path)
  float* sp = (float*)smem;     // [4][DOUT] (POOL path)
  float pacc[NCOL];
  if (POOL) {
#pragma unroll
    for (int c = 0; c < NCOL; c++) pacc[c] = 0.f;
  }
#pragma unroll
  for (int r = 0; r < 4; r++) {
    const int row = rg2 * 16 + q * 4 + r;
    const float m1 = sstat[(row * 2 + 0) * 2 + 0] + sstat[(row * 2 + 1) * 2 + 0];
    const float m2 = sstat[(row * 2 + 0) * 2 + 1] + sstat[(row * 2 + 1) * 2 + 1];
    const float mu = m1 / DOUT;
    const float rstd = rsqrtf(m2 / DOUT - mu * mu + 1e-6f);
    float mval = 0.f;
    if (POOL) mval = mask[(size_t)b * NPTS + i0 + row];
#pragma unroll
    for (int c = 0; c < NCOL; c++) {
      const int dco = (ch * NCOL + c) * 16 + m;
      const float v = (oacc[c][r] + bcol[c] - mu) * rstd * g[dco] + be[dco];
      const float act = v / (1.0f + __expf(-v));
      if (POOL) pacc[c] = fmaf(act, mval, pacc[c]);
      else lt[row * DOUT + dco] = f2bf(act);
    }
  }
  if (POOL) {
#pragma unroll
    for (int c = 0; c < NCOL; c++) {
      float v = pacc[c];
      v += __shfl_xor(v, 16, 64);
      v += __shfl_xor(v, 32, 64);   // sum over q -> this wave's 16 rows
      if (q == 0) sp[rg2 * DOUT + (ch * NCOL + c) * 16 + m] = v;
    }
    __syncthreads();
    if (tid < DOUT)
      partial[((size_t)b * (NPTS / 64) + blockIdx.x) * DOUT + tid] =
          (sp[tid] + sp[DOUT + tid]) + (sp[2 * DOUT + tid] + sp[3 * DOUT + tid]);
  } else {
    __syncthreads();
    if (tid < DOUT) {
      ushort tmp[64];
#pragma unroll
      for (int r = 0; r < 64; r++) tmp[r] = lt[r * DOUT + tid];
      ushort* dst = hout + ((size_t)b * DOUT + tid) * NPTS + i0;
#pragma unroll
      for (int c = 0; c < 8; c++)
        *(uint4*)(dst + c * 8) = *(uint4*)&tmp[c * 8];
    }
  }
}

// ---------------------------------------------------------------------------
// readout: reduce 32 partial rows per batch, divide by count, Dense(256->128)
// ---------------------------------------------------------------------------
__global__ __launch_bounds__(256) void readout_kernel(
    const float* __restrict__ partial, const float* __restrict__ mask,
    const float* __restrict__ Wz, const float* __restrict__ bz,
    float* __restrict__ out) {
  const int b = blockIdx.x;
  const int tid = threadIdx.x;
  const float* pb = partial + (size_t)b * (NPTS / 64) * 256;
  float s0 = 0.f, s1 = 0.f, s2 = 0.f, s3 = 0.f;
#pragma unroll
  for (int p = 0; p < NPTS / 64; p += 4) {
    s0 += pb[(size_t)(p + 0) * 256 + tid];
    s1 += pb[(size_t)(p + 1) * 256 + tid];
    s2 += pb[(size_t)(p + 2) * 256 + tid];
    s3 += pb[(size_t)(p + 3) * 256 + tid];
  }
  const float s = (s0 + s1) + (s2 + s3);
  const float* mb = mask + (size_t)b * NPTS;
  float c = 0.f;
  for (int n = tid; n < NPTS; n += 256) c += mb[n];
  __shared__ float red[256];
  red[tid] = c;
  __syncthreads();
  for (int off = 128; off > 0; off >>= 1) {
    if (tid < off) red[tid] += red[tid + off];
    __syncthreads();
  }
  const float cnt = fmaxf(red[0], 1.0f);
  __shared__ float gf[256];
  gf[tid] = s / cnt;
  __syncthreads();
  if (tid < LATENT) {
    float z = bz[tid];
#pragma unroll 4
    for (int d = 0; d < 256; d++) z += gf[d] * Wz[(size_t)d * LATENT + tid];
    out[(size_t)b * LATENT + tid] = z;
  }
}

// ---------------------------------------------------------------------------
extern "C" void kernel_launch(void* const* d_in, const int* in_sizes, int n_in,
                              void* d_out, int out_size, void* d_ws, size_t ws_size,
                              hipStream_t stream) {
  const float* x    = (const float*)d_in[0];
  const float* mask = (const float*)d_in[1];
  const float* W0   = (const float*)d_in[2];
  const float* b0   = (const float*)d_in[3];
  const float* g0   = (const float*)d_in[4];
  const float* be0  = (const float*)d_in[5];
  const float* W1   = (const float*)d_in[6];
  const float* b1   = (const float*)d_in[7];
  const float* g1   = (const float*)d_in[8];
  const float* be1  = (const float*)d_in[9];
  const float* W2   = (const float*)d_in[10];
  const float* b2   = (const float*)d_in[11];
  const float* g2   = (const float*)d_in[12];
  const float* be2  = (const float*)d_in[13];
  const float* Wz   = (const float*)d_in[14];
  const float* bz   = (const float*)d_in[15];
  float* out = (float*)d_out;

  // workspace layout (bytes, 16B-aligned regions)
  char* ws = (char*)d_ws;
  float4* pnt     = (float4*)(ws);             // 262144
  ushort* h1T     = (ushort*)(ws + 262144);    // 2097152
  ushort* h2T     = (ushort*)(ws + 2359296);   // 4194304
  float*  partial = (float*)(ws + 6553600);    // 8*32*256*4 = 262144
  ushort* WT1     = (ushort*)(ws + 6815744);   // 16384
  ushort* WT2     = (ushort*)(ws + 6832128);   // 65536
  // total ~6.9 MB

  // prep + both W transposes in one launch
  setup_kernel<<<dim3(18), dim3(256), 0, stream>>>(x, mask, pnt, W1, WT1, W2, WT2);

  // layer 0: agg (D=3) + dense 3->64 + LN + swish, fused
  layer0_kernel<<<dim3(NPTS / 64, BATCH), dim3(512), 0, stream>>>(
      pnt, W0, b0, g0, be0, h1T);

  // layer 1 (64 -> 128): fused MFMA agg + MFMA dense + LN + swish
  fused_layer<64, 128, false><<<dim3(NPTS / 64, BATCH), dim3(512), 0, stream>>>(
      pnt, h1T, WT1, b1, g1, be1, h2T, nullptr, nullptr);

  // layer 2 (128 -> 256): fused + masked-sum pooling
  fused_layer<128, 256, true><<<dim3(NPTS / 64, BATCH), dim3(512), 0, stream>>>(
      pnt, h2T, WT2, b2, g2, be2, nullptr, mask, partial);

  // readout
  readout_kernel<<<dim3(BATCH), dim3(256), 0, stream>>>(partial, mask, Wz, bz, out);
}

// Round 9
// 175.128 us; speedup vs baseline: 1.6056x; 1.1238x over previous
//
#include <hip/hip_runtime.h>
#include <hip/hip_bf16.h>

#define BATCH 8
#define NPTS 2048
#define LATENT 128

typedef __attribute__((ext_vector_type(8))) short short8;
typedef __attribute__((ext_vector_type(4))) float f32x4;

__device__ __forceinline__ ushort f2bf(float f) {
  unsigned int b = __float_as_uint(f);
  b += 0x7FFF + ((b >> 16) & 1);
  return (ushort)(b >> 16);
}
__device__ __forceinline__ float bf2f(ushort u) {
  return __uint_as_float(((unsigned int)u) << 16);
}
// packed bf16 convert (v_cvt_pk_bf16_f32 on gfx950), RNE — same as f2bf
__device__ __forceinline__ unsigned int pkbf(float a, float b) {
  __hip_bfloat162 h = __float22bfloat162_rn(make_float2(a, b));
  return *(unsigned int*)&h;
}

typedef unsigned int __attribute__((address_space(1))) gas_uint;
typedef unsigned int __attribute__((address_space(3))) las_uint;
__device__ __forceinline__ void gl_lds16(const void* g, void* l) {
  __builtin_amdgcn_global_load_lds((const gas_uint*)g, (las_uint*)l, 16, 0, 0);
}

// log2(e) and sqrt(2*log2(e)) — points are stored in exp2-space
#define L2E 1.4426950408889634f
#define SC2 1.6986436f

// ---------------------------------------------------------------------------
// setup: bid 0..7 = prep (centroid + pnt), 8..9 = WT1, 10..17 = WT2,
//        18..25 = WzT. WT[n][k] = bf16(W[k][n]).
// pnt[b][n] = (SC2*xc, -|xc|^2*L2E): pi.w+pj.w+dot(pi.xyz,pj.xyz) = -L2E*dist.
// ---------------------------------------------------------------------------
__device__ __forceinline__ void wtrans_tile(const float* __restrict__ W,
    ushort* __restrict__ WT, int K, int N, int n0, int k0, int tid) {
  __shared__ ushort s[64][72];
  for (int i = tid; i < 64 * 64; i += 256) {
    const int kl = i >> 6, nl = i & 63;
    s[kl][nl] = f2bf(W[(size_t)(k0 + kl) * N + n0 + nl]);
  }
  __syncthreads();
  for (int i = tid; i < 64 * 64; i += 256) {
    const int nl = i >> 6, kl = i & 63;
    WT[(size_t)(n0 + nl) * K + k0 + kl] = s[kl][nl];
  }
}

__global__ __launch_bounds__(256) void setup_kernel(const float* __restrict__ x,
    const float* __restrict__ mask, float4* __restrict__ pnt,
    const float* __restrict__ W1, ushort* __restrict__ WT1,
    const float* __restrict__ W2, ushort* __restrict__ WT2,
    const float* __restrict__ Wz, ushort* __restrict__ WzT) {
  const int bid = blockIdx.x;
  const int tid = threadIdx.x;
  if (bid >= 8) {
    if (bid < 10) wtrans_tile(W1, WT1, 64, 128, (bid - 8) * 64, 0, tid);
    else if (bid < 18) {
      const int idx = bid - 10;
      wtrans_tile(W2, WT2, 128, 256, (idx & 3) * 64, (idx >> 2) * 64, tid);
    } else {
      const int idx = bid - 18;
      wtrans_tile(Wz, WzT, 256, 128, (idx & 1) * 64, (idx >> 1) * 64, tid);
    }
    return;
  }
  const int b = bid;
  const float* xb = x + (size_t)b * NPTS * 3;
  const float* mb = mask + (size_t)b * NPTS;
  float s0 = 0.f, s1 = 0.f, s2 = 0.f, c = 0.f;
  for (int n = tid; n < NPTS; n += 256) {
    float m = mb[n];
    s0 += xb[n * 3 + 0] * m;
    s1 += xb[n * 3 + 1] * m;
    s2 += xb[n * 3 + 2] * m;
    c += m;
  }
  __shared__ float red[4][256];
  red[0][tid] = s0; red[1][tid] = s1; red[2][tid] = s2; red[3][tid] = c;
  __syncthreads();
  for (int off = 128; off > 0; off >>= 1) {
    if (tid < off) {
      red[0][tid] += red[0][tid + off];
      red[1][tid] += red[1][tid + off];
      red[2][tid] += red[2][tid + off];
      red[3][tid] += red[3][tid + off];
    }
    __syncthreads();
  }
  const float cnt = fmaxf(red[3][0], 1.0f);
  const float c0 = red[0][0] / cnt, c1 = red[1][0] / cnt, c2 = red[2][0] / cnt;
  float4* pb = pnt + (size_t)b * NPTS;
  for (int n = tid; n < NPTS; n += 256) {
    const float a0 = xb[n * 3 + 0] - c0;
    const float a1 = xb[n * 3 + 1] - c1;
    const float a2 = xb[n * 3 + 2] - c2;
    pb[n] = make_float4(a0 * SC2, a1 * SC2, a2 * SC2,
                        -(a0 * a0 + a1 * a1 + a2 * a2) * L2E);
  }
}

// ---------------------------------------------------------------------------
// layer 0 fused: aggregation (D=3, VALU, 8-way j-split) + dense 3->64 +
// LN + swish + transposed bf16 write h1T[b][d][n]. 64 rows/block, 512 thr.
// ---------------------------------------------------------------------------
__global__ __launch_bounds__(512) void layer0_kernel(
    const float4* __restrict__ pnt, const float* __restrict__ W,
    const float* __restrict__ bias, const float* __restrict__ g,
    const float* __restrict__ be, ushort* __restrict__ hout) {
  const int b = blockIdx.y;
  const int i0 = blockIdx.x * 64;
  const int tid = threadIdx.x;
  const int il = tid & 63, part = tid >> 6;   // 8 j-parts
  const float4* pb = pnt + (size_t)b * NPTS;
  const float4 pi = pb[i0 + il];
  float a0 = 0.f, a1 = 0.f, a2 = 0.f, dn = 0.f;
#pragma unroll 8
  for (int j = part * 256; j < part * 256 + 256; j++) {
    const float4 pj = pb[j];
    float arg = pi.w + pj.w;
    arg = fmaf(pi.x, pj.x, arg);
    arg = fmaf(pi.y, pj.y, arg);
    arg = fmaf(pi.z, pj.z, arg);
    const float w = __builtin_amdgcn_exp2f(arg);
    a0 = fmaf(w, pj.x, a0);
    a1 = fmaf(w, pj.y, a1);
    a2 = fmaf(w, pj.z, a2);
    dn += w;
  }
  __shared__ float4 sred[8][64];
  __shared__ float srow[64 * 3];
  __shared__ ushort lt[64][64];
  sred[part][il] = make_float4(a0, a1, a2, dn);
  __syncthreads();
  if (tid < 64) {
    float A0 = 0.f, A1 = 0.f, A2 = 0.f, DN = 0.f;
#pragma unroll
    for (int p = 0; p < 8; p++) {
      const float4 r = sred[p][tid];
      A0 += r.x; A1 += r.y; A2 += r.z; DN += r.w;
    }
    const float inv = 1.0f / (DN * SC2);   // undo SC2 scaling of xyz
    srow[tid * 3 + 0] = A0 * inv;
    srow[tid * 3 + 1] = A1 * inv;
    srow[tid * 3 + 2] = A2 * inv;
  }
  __syncthreads();
  const int wv = tid >> 6, lane = tid & 63;
  const float w0c = W[lane], w1c = W[64 + lane], w2c = W[128 + lane];
  const float gv = g[lane], bev = be[lane], bv = bias[lane];
#pragma unroll
  for (int r = 0; r < 8; r++) {
    const int row = wv * 8 + r;
    float o = bv;
    o = fmaf(srow[row * 3 + 0], w0c, o);
    o = fmaf(srow[row * 3 + 1], w1c, o);
    o = fmaf(srow[row * 3 + 2], w2c, o);
    float m1 = o, m2 = o * o;
#pragma unroll
    for (int off = 32; off > 0; off >>= 1) {
      m1 += __shfl_xor(m1, off, 64);
      m2 += __shfl_xor(m2, off, 64);
    }
    const float mu = m1 / 64.f;
    const float rstd = rsqrtf(m2 / 64.f - mu * mu + 1e-6f);
    const float v = (o - mu) * rstd * gv + bev;
    const float act = v / (1.0f + __expf(-v));
    lt[row][lane] = f2bf(act);
  }
  __syncthreads();
  if (tid < 64) {
    ushort tmp[64];
#pragma unroll
    for (int r = 0; r < 64; r++) tmp[r] = lt[r][tid];
    ushort* dst = hout + ((size_t)b * 64 + tid) * NPTS + i0;
#pragma unroll
    for (int c = 0; c < 8; c++)
      *(uint4*)(dst + c * 8) = *(uint4*)&tmp[c * 8];
  }
}

// ---------------------------------------------------------------------------
// FUSED layer v6: 32 rows/block, 256 threads, 4 waves = {j-half}x{j-sub32};
// each wave owns all 32 rows (2 A-frags => every B LDS read feeds 2 MFMAs).
// Grid = 512 -> 2 independent blocks/CU (barrier decoupling). Packed bf16
// cvt for A-frags. h staged by global_load_lds with XOR chunk swizzle.
// 1-slot 4-phase split-K combine; MFMA dense epilogue; LN+swish; POOL.
// ---------------------------------------------------------------------------
template <int DIN, int DOUT, bool POOL, int MINW>
__global__ __launch_bounds__(256, MINW) void fused_layer(
    const float4* __restrict__ pnt, const ushort* __restrict__ hT,
    const ushort* __restrict__ WT, const float* __restrict__ bias,
    const float* __restrict__ g, const float* __restrict__ be,
    ushort* __restrict__ hout, const float* __restrict__ mask,
    float* __restrict__ partial) {
  constexpr int NT = DIN / 16;
  constexpr int HALF = NPTS / 2;
  constexpr int TILES = HALF / 64;      // 16
  constexpr int NCOL = DOUT / 32;       // dense col-tiles per wave
  constexpr int PS = DIN + 8;           // srow pitch (ushorts)
  constexpr int PN = DIN + 4;           // snum pitch (floats)
  constexpr int SHT_B = 2 * 2 * DIN * 64 * 2;   // [buf][half][DIN][64] ushort
  constexpr int SPNT_B = 2 * 2 * 64 * 16;       // [buf][half][64] float4
  constexpr int LOOP_B = SHT_B + SPNT_B;
  constexpr int SNUM_B = 32 * PN * 4;           // [row][d] single slot
  constexpr int OFF_SROW = SNUM_B;              // [32][PS] ushort
  constexpr int OFF_SDEN = OFF_SROW + 32 * PS * 2;  // [32] float
  constexpr int OFF_SINV = OFF_SDEN + 128;      // [32] float
  constexpr int OFF_SSTAT = OFF_SINV + 128;     // [32][2][2] float
  constexpr int EPI_B = OFF_SSTAT + 512;
  constexpr int SMEM_B = LOOP_B > EPI_B ? LOOP_B : EPI_B;
  __shared__ __align__(16) char smem[SMEM_B];
  ushort* sht = (ushort*)smem;
  float4* spnt = (float4*)(smem + SHT_B);

  const int b = blockIdx.y;
  const int i0 = blockIdx.x * 32;
  const int tid = threadIdx.x;
  const int wv = tid >> 6, lane = tid & 63;
  const int h = wv >> 1;   // j half
  const int u = wv & 1;    // 32-j sub-tile
  const int m = lane & 15, q = lane >> 4;
  const float4* pb = pnt + (size_t)b * NPTS;
  const ushort* hb = hT + (size_t)b * DIN * NPTS;

  const float4 pi0 = pb[i0 + m];        // A-rows 0..15
  const float4 pi1 = pb[i0 + 16 + m];   // A-rows 16..31

  f32x4 acc0[NT], acc1[NT];
#pragma unroll
  for (int nt = 0; nt < NT; nt++)
#pragma unroll
    for (int e = 0; e < 4; e++) { acc0[nt][e] = 0.f; acc1[nt][e] = 0.f; }
  float dacc0 = 0.f, dacc1 = 0.f;

  constexpr int NCH = DIN / 16;            // sht DMA issues per wave
  const int srow8 = lane >> 3;
  const int scsrc = (lane & 7) ^ srow8;    // XOR-swizzled source chunk
  const int jsw = ((lane & 7) << 3) | (lane >> 3);  // spnt swizzle (involution)

  auto stage = [&](int t, int bf) {
    const int jb = t * 64;
#pragma unroll
    for (int i = 0; i < NCH; i++) {
      const int idx = wv * NCH + i;
      const int h2 = idx / (DIN / 8);
      const int oct = idx % (DIN / 8);
      const int row = oct * 8 + srow8;
      gl_lds16(hb + (size_t)row * NPTS + h2 * HALF + jb + scsrc * 8,
               sht + ((size_t)(bf * 2 + h2) * DIN + oct * 8) * 64);
    }
    if (wv == 0) {
#pragma unroll
      for (int h2 = 0; h2 < 2; h2++)
        gl_lds16(pb + h2 * HALF + jb + jsw, spnt + (bf * 2 + h2) * 64);
    }
  };

  stage(0, 0);
  __syncthreads();
  for (int t = 0; t < TILES; t++) {
    const int bf = t & 1;
    if (t + 1 < TILES) stage(t + 1, bf ^ 1);   // DMA into other buffer
    float w0a[8], w1a[8];
#pragma unroll
    for (int jj = 0; jj < 8; jj++) {
      const float4 pj = spnt[(bf * 2 + h) * 64 + ((jj << 3) | (u * 4 + q))];
      float a0 = pi0.w + pj.w;
      a0 = fmaf(pi0.x, pj.x, a0);
      a0 = fmaf(pi0.y, pj.y, a0);
      a0 = fmaf(pi0.z, pj.z, a0);
      float a1 = pi1.w + pj.w;
      a1 = fmaf(pi1.x, pj.x, a1);
      a1 = fmaf(pi1.y, pj.y, a1);
      a1 = fmaf(pi1.z, pj.z, a1);
      w0a[jj] = __builtin_amdgcn_exp2f(a0);   // exp(-dist)
      w1a[jj] = __builtin_amdgcn_exp2f(a1);
      dacc0 += w0a[jj]; dacc1 += w1a[jj];
    }
    unsigned int au0[4], au1[4];
#pragma unroll
    for (int p = 0; p < 4; p++) {
      au0[p] = pkbf(w0a[2 * p], w0a[2 * p + 1]);
      au1[p] = pkbf(w1a[2 * p], w1a[2 * p + 1]);
    }
    const short8 af0 = *(short8*)au0;
    const short8 af1 = *(short8*)au1;
#pragma unroll
    for (int nt = 0; nt < NT; nt++) {
      const int d = nt * 16 + m;
      const short8 bfr = *(const short8*)
          &sht[((size_t)(bf * 2 + h) * DIN + d) * 64 + (((u * 4 + q) ^ (m & 7)) << 3)];
      acc0[nt] = __builtin_amdgcn_mfma_f32_16x16x32_bf16(af0, bfr, acc0[nt], 0, 0, 0);
      acc1[nt] = __builtin_amdgcn_mfma_f32_16x16x32_bf16(af1, bfr, acc1[nt], 0, 0, 0);
    }
    __syncthreads();
  }

  // ---- 1-slot 4-phase split-K combine in LDS (aliased over dead staging) --
  float* snum = (float*)smem;                    // [32][PN]
  ushort* srow = (ushort*)(smem + OFF_SROW);     // [32][PS]
  float* sden = (float*)(smem + OFF_SDEN);
  float* sinv = (float*)(smem + OFF_SINV);
  float* sstat = (float*)(smem + OFF_SSTAT);

  dacc0 += __shfl_xor(dacc0, 16, 64);
  dacc0 += __shfl_xor(dacc0, 32, 64);
  dacc1 += __shfl_xor(dacc1, 16, 64);
  dacc1 += __shfl_xor(dacc1, 32, 64);
  for (int p = 0; p < 4; p++) {
    if (wv == p) {
      if (p == 0) {
#pragma unroll
        for (int nt = 0; nt < NT; nt++)
#pragma unroll
          for (int r = 0; r < 4; r++) {
            snum[(q * 4 + r) * PN + nt * 16 + m] = acc0[nt][r];
            snum[(16 + q * 4 + r) * PN + nt * 16 + m] = acc1[nt][r];
          }
        if (q == 0) { sden[m] = dacc0; sden[16 + m] = dacc1; }
      } else {
#pragma unroll
        for (int nt = 0; nt < NT; nt++)
#pragma unroll
          for (int r = 0; r < 4; r++) {
            snum[(q * 4 + r) * PN + nt * 16 + m] += acc0[nt][r];
            snum[(16 + q * 4 + r) * PN + nt * 16 + m] += acc1[nt][r];
          }
        if (q == 0) { sden[m] += dacc0; sden[16 + m] += dacc1; }
      }
    }
    __syncthreads();
  }
  if (tid < 32) sinv[tid] = 1.0f / sden[tid];
  __syncthreads();
  for (int idx = tid; idx < 32 * (DIN / 2); idx += 256) {
    const int r = idx / (DIN / 2), c2 = idx % (DIN / 2);
    const float v0 = snum[r * PN + 2 * c2] * sinv[r];
    const float v1 = snum[r * PN + 2 * c2 + 1] * sinv[r];
    *(unsigned int*)&srow[r * PS + 2 * c2] = pkbf(v0, v1);
  }
  __syncthreads();

  // ---- dense via MFMA: rows (wv>>1)*16.., col-half (wv&1) ----
  const int rg2 = wv >> 1, ch = wv & 1;
  short8 afrag[DIN / 32];
#pragma unroll
  for (int kt = 0; kt < DIN / 32; kt++)
    afrag[kt] = *(const short8*)&srow[(rg2 * 16 + m) * PS + kt * 32 + q * 8];
  f32x4 oacc[NCOL];
#pragma unroll
  for (int c = 0; c < NCOL; c++)
#pragma unroll
    for (int e = 0; e < 4; e++) oacc[c][e] = 0.f;
#pragma unroll
  for (int c = 0; c < NCOL; c++) {
    const int n0 = (ch * NCOL + c) * 16;
#pragma unroll
    for (int kt = 0; kt < DIN / 32; kt++) {
      const short8 bfrag = *(const short8*)(WT + (size_t)(n0 + m) * DIN + kt * 32 + q * 8);
      oacc[c] = __builtin_amdgcn_mfma_f32_16x16x32_bf16(afrag[kt], bfrag, oacc[c], 0, 0, 0);
    }
  }

  // ---- LN stats across both col-halves via LDS ----
  float bcol[NCOL];
#pragma unroll
  for (int c = 0; c < NCOL; c++) bcol[c] = bias[(ch * NCOL + c) * 16 + m];
#pragma unroll
  for (int r = 0; r < 4; r++) {
    float m1 = 0.f, m2 = 0.f;
#pragma unroll
    for (int c = 0; c < NCOL; c++) {
      const float v = oacc[c][r] + bcol[c];
      m1 += v; m2 += v * v;
    }
#pragma unroll
    for (int off = 8; off > 0; off >>= 1) {
      m1 += __shfl_xor(m1, off, 64);
      m2 += __shfl_xor(m2, off, 64);
    }
    if (m == 0) {
      const int row = rg2 * 16 + q * 4 + r;
      sstat[(row * 2 + ch) * 2 + 0] = m1;
      sstat[(row * 2 + ch) * 2 + 1] = m2;
    }
  }
  __syncthreads();

  ushort* lt = (ushort*)smem;   // [32][DOUT], aliases dead snum (TOUT path)
  float* sp = (float*)smem;     // [2][DOUT] (POOL path)
  float pacc[NCOL];
  if (POOL) {
#pragma unroll
    for (int c = 0; c < NCOL; c++) pacc[c] = 0.f;
  }
#pragma unroll
  for (int r = 0; r < 4; r++) {
    const int row = rg2 * 16 + q * 4 + r;
    const float m1 = sstat[(row * 2 + 0) * 2 + 0] + sstat[(row * 2 + 1) * 2 + 0];
    const float m2 = sstat[(row * 2 + 0) * 2 + 1] + sstat[(row * 2 + 1) * 2 + 1];
    const float mu = m1 / DOUT;
    const float rstd = rsqrtf(m2 / DOUT - mu * mu + 1e-6f);
    float mval = 0.f;
    if (POOL) mval = mask[(size_t)b * NPTS + i0 + row];
#pragma unroll
    for (int c = 0; c < NCOL; c++) {
      const int dco = (ch * NCOL + c) * 16 + m;
      const float v = (oacc[c][r] + bcol[c] - mu) * rstd * g[dco] + be[dco];
      const float act = v / (1.0f + __expf(-v));
      if (POOL) pacc[c] = fmaf(act, mval, pacc[c]);
      else lt[row * DOUT + dco] = f2bf(act);
    }
  }
  if (POOL) {
#pragma unroll
    for (int c = 0; c < NCOL; c++) {
      float v = pacc[c];
      v += __shfl_xor(v, 16, 64);
      v += __shfl_xor(v, 32, 64);   // sum over q -> this wave's 16 rows
      if (q == 0) sp[rg2 * DOUT + (ch * NCOL + c) * 16 + m] = v;
    }
    __syncthreads();
    if (tid < DOUT)
      partial[((size_t)b * (NPTS / 32) + blockIdx.x) * DOUT + tid] =
          sp[tid] + sp[DOUT + tid];
  } else {
    __syncthreads();
    if (tid < DOUT) {
      ushort tmp[32];
#pragma unroll
      for (int r = 0; r < 32; r++) tmp[r] = lt[r * DOUT + tid];
      ushort* dst = hout + ((size_t)b * DOUT + tid) * NPTS + i0;
#pragma unroll
      for (int c = 0; c < 4; c++)
        *(uint4*)(dst + c * 8) = *(uint4*)&tmp[c * 8];
    }
  }
}

// ---------------------------------------------------------------------------
// readout: reduce 64 partial rows/batch, /count, Dense(256->128) with
// bf16 WzT[n][k] (contiguous dwordx4 loads, dot split across 2 half-waves).
// ---------------------------------------------------------------------------
__global__ __launch_bounds__(256) void readout_kernel(
    const float* __restrict__ partial, const float* __restrict__ mask,
    const ushort* __restrict__ WzT, const float* __restrict__ bz,
    float* __restrict__ out) {
  const int b = blockIdx.x;
  const int tid = threadIdx.x;
  const float* pb = partial + (size_t)b * (NPTS / 32) * 256;
  float s0 = 0.f, s1 = 0.f, s2 = 0.f, s3 = 0.f;
#pragma unroll 4
  for (int p = 0; p < NPTS / 32; p += 4) {
    s0 += pb[(size_t)(p + 0) * 256 + tid];
    s1 += pb[(size_t)(p + 1) * 256 + tid];
    s2 += pb[(size_t)(p + 2) * 256 + tid];
    s3 += pb[(size_t)(p + 3) * 256 + tid];
  }
  const float s = (s0 + s1) + (s2 + s3);
  const float* mb = mask + (size_t)b * NPTS;
  float c = 0.f;
  for (int n = tid; n < NPTS; n += 256) c += mb[n];
  __shared__ float red[256];
  red[tid] = c;
  __syncthreads();
  for (int off = 128; off > 0; off >>= 1) {
    if (tid < off) red[tid] += red[tid + off];
    __syncthreads();
  }
  const float cnt = fmaxf(red[0], 1.0f);
  __shared__ float gf[256];
  gf[tid] = s / cnt;
  __syncthreads();
  const int col = tid & 127, part = tid >> 7;   // split dot over 2 groups
  float z = 0.f;
  const ushort* wr = WzT + (size_t)col * 256 + part * 128;
  const float* gp = gf + part * 128;
#pragma unroll 4
  for (int d = 0; d < 128; d += 8) {
    const short8 w8 = *(const short8*)(wr + d);
#pragma unroll
    for (int e = 0; e < 8; e++)
      z = fmaf(gp[d + e], bf2f((ushort)w8[e]), z);
  }
  __shared__ float zred[256];
  zred[tid] = z;
  __syncthreads();
  if (tid < LATENT)
    out[(size_t)b * LATENT + tid] = bz[tid] + zred[tid] + zred[128 + tid];
}

// ---------------------------------------------------------------------------
extern "C" void kernel_launch(void* const* d_in, const int* in_sizes, int n_in,
                              void* d_out, int out_size, void* d_ws, size_t ws_size,
                              hipStream_t stream) {
  const float* x    = (const float*)d_in[0];
  const float* mask = (const float*)d_in[1];
  const float* W0   = (const float*)d_in[2];
  const float* b0   = (const float*)d_in[3];
  const float* g0   = (const float*)d_in[4];
  const float* be0  = (const float*)d_in[5];
  const float* W1   = (const float*)d_in[6];
  const float* b1   = (const float*)d_in[7];
  const float* g1   = (const float*)d_in[8];
  const float* be1  = (const float*)d_in[9];
  const float* W2   = (const float*)d_in[10];
  const float* b2   = (const float*)d_in[11];
  const float* g2   = (const float*)d_in[12];
  const float* be2  = (const float*)d_in[13];
  const float* Wz   = (const float*)d_in[14];
  const float* bz   = (const float*)d_in[15];
  float* out = (float*)d_out;

  // workspace layout (bytes, 16B-aligned regions)
  char* ws = (char*)d_ws;
  float4* pnt     = (float4*)(ws);             // 262144
  ushort* h1T     = (ushort*)(ws + 262144);    // 2097152
  ushort* h2T     = (ushort*)(ws + 2359296);   // 4194304
  float*  partial = (float*)(ws + 6553600);    // 8*64*256*4 = 524288
  ushort* WT1     = (ushort*)(ws + 7077888);   // 16384
  ushort* WT2     = (ushort*)(ws + 7094272);   // 65536
  ushort* WzT     = (ushort*)(ws + 7159808);   // 128*256*2 = 65536
  // total ~7.2 MB

  // prep + all W transposes in one launch
  setup_kernel<<<dim3(26), dim3(256), 0, stream>>>(
      x, mask, pnt, W1, WT1, W2, WT2, Wz, WzT);

  // layer 0: agg (D=3) + dense 3->64 + LN + swish, fused
  layer0_kernel<<<dim3(NPTS / 64, BATCH), dim3(512), 0, stream>>>(
      pnt, W0, b0, g0, be0, h1T);

  // layer 1 (64 -> 128): fused MFMA agg + MFMA dense + LN + swish
  fused_layer<64, 128, false, 4><<<dim3(NPTS / 32, BATCH), dim3(256), 0, stream>>>(
      pnt, h1T, WT1, b1, g1, be1, h2T, nullptr, nullptr);

  // layer 2 (128 -> 256): fused + masked-sum pooling
  fused_layer<128, 256, true, 2><<<dim3(NPTS / 32, BATCH), dim3(256), 0, stream>>>(
      pnt, h2T, WT2, b2, g2, be2, nullptr, mask, partial);

  // readout
  readout_kernel<<<dim3(BATCH), dim3(256), 0, stream>>>(partial, mask, WzT, bz, out);
}